// Round 1
// baseline (737.234 us; speedup 1.0000x reference)
//
#include <hip/hip_runtime.h>
#include <hip/hip_bf16.h>

// Problem constants (fixed by reference)
#define N_NODES 20000
#define NUM_DRUGS 2048
#define NUM_DPI 200000
#define E2 400000          // 2*NUM_DPI directed edges
#define CDIM 256           // IN_C == EMB == 256
#define HID 512
#define N_CL 8
#define BATCH 16384

// ---------------------------------------------------------------------------
// zero counters
__global__ void zero_counts(int* cnt_col, int* cur_col, int* cnt_drug, int* cur_drug,
                            int* clcnt, int* curcl) {
    int i = blockIdx.x * blockDim.x + threadIdx.x;
    if (i < N_NODES) { cnt_col[i] = 0; cur_col[i] = 0; }
    if (i < NUM_DRUGS) { cnt_drug[i] = 0; cur_drug[i] = 0; }
    if (i < N_CL) { clcnt[i] = 0; curcl[i] = 0; }
}

// count occurrences: node in-degree (excl self-loop), per-drug DPI count, per-cl rows
__global__ void count_all(const int* __restrict__ ei, const int* __restrict__ ecl,
                          int* cnt_col, int* cnt_drug, int* clcnt) {
    int e = blockIdx.x * blockDim.x + threadIdx.x;
    if (e < E2) atomicAdd(&cnt_col[ei[E2 + e]], 1);          // edge_index[1][e]
    if (e < NUM_DPI) atomicAdd(&cnt_drug[ei[e]], 1);         // drug id
    if (e < BATCH) atomicAdd(&clcnt[ecl[e]], 1);
}

// single-block exclusive scan: ptr[0..n] from counts[0..n-1]
__global__ void scan_block(const int* __restrict__ counts, int* __restrict__ ptr, int n) {
    __shared__ int sums[1024];
    int t = threadIdx.x;
    int per = (n + 1023) / 1024;
    int start = t * per;
    int end = start + per; if (end > n) end = n;
    int s = 0;
    for (int i = start; i < end; i++) s += counts[i];
    sums[t] = s;
    __syncthreads();
    for (int off = 1; off < 1024; off <<= 1) {
        int v = (t >= off) ? sums[t - off] : 0;
        __syncthreads();
        sums[t] += v;
        __syncthreads();
    }
    int base = (t == 0) ? 0 : sums[t - 1];
    for (int i = start; i < end; i++) {
        ptr[i] = base;
        base += counts[i];
    }
    if (t == 1023) ptr[n] = sums[1023];
}

// fill CSR adjacency lists + perm (rows sorted by cell line) + dinv
__global__ void fill_all(const int* __restrict__ ei, const int* __restrict__ ecl,
                         const int* __restrict__ col_ptr, int* cur_col, int* adj_col,
                         const int* __restrict__ drug_ptr, int* cur_drug, int* adj_drug,
                         const int* __restrict__ cloff, int* curcl, int* perm,
                         const int* __restrict__ cnt_col, float* dinv) {
    int e = blockIdx.x * blockDim.x + threadIdx.x;
    if (e < E2) {
        int c = ei[E2 + e];                       // target node
        int pos = col_ptr[c] + atomicAdd(&cur_col[c], 1);
        adj_col[pos] = ei[e];                     // source node
    }
    if (e < NUM_DPI) {
        int d = ei[e];                            // drug
        int pos = drug_ptr[d] + atomicAdd(&cur_drug[d], 1);
        adj_drug[pos] = ei[E2 + e];               // protein
    }
    if (e < BATCH) {
        int c = ecl[e];
        int pos = cloff[c] + atomicAdd(&curcl[c], 1);
        perm[pos] = e;
    }
    if (e < N_NODES) {
        dinv[e] = rsqrtf((float)(cnt_col[e] + 1));  // +1 self-loop
    }
}

// ---------------------------------------------------------------------------
// generic fp32 GEMM: C[M,N] = A[M,K] @ B[K,N]; 64x64 tile, 256 thr, 4x4/thr
__global__ __launch_bounds__(256) void gemm64(const float* __restrict__ A,
                                              const float* __restrict__ Bm,
                                              float* __restrict__ C,
                                              int M, int K, int N) {
    __shared__ float As[16][68];
    __shared__ float Bs[16][68];
    int t = threadIdx.x;
    int tx = t & 15, ty = t >> 4;
    int rowBase = blockIdx.x * 64;
    int colBase = blockIdx.y * 64;
    int ar = t >> 2, ak = (t & 3) * 4;
    int bk = t >> 4, bn = (t & 15) * 4;
    float acc[4][4] = {};
    for (int kk = 0; kk < K; kk += 16) {
        float4 av = make_float4(0.f, 0.f, 0.f, 0.f);
        int gr = rowBase + ar;
        if (gr < M) av = *(const float4*)(A + (size_t)gr * K + kk + ak);
        As[ak + 0][ar] = av.x; As[ak + 1][ar] = av.y;
        As[ak + 2][ar] = av.z; As[ak + 3][ar] = av.w;
        *(float4*)&Bs[bk][bn] = *(const float4*)(Bm + (size_t)(kk + bk) * N + colBase + bn);
        __syncthreads();
#pragma unroll
        for (int k = 0; k < 16; k++) {
            float a0 = As[k][ty * 4 + 0], a1 = As[k][ty * 4 + 1];
            float a2 = As[k][ty * 4 + 2], a3 = As[k][ty * 4 + 3];
            float b0 = Bs[k][tx * 4 + 0], b1 = Bs[k][tx * 4 + 1];
            float b2 = Bs[k][tx * 4 + 2], b3 = Bs[k][tx * 4 + 3];
            acc[0][0] = fmaf(a0, b0, acc[0][0]); acc[0][1] = fmaf(a0, b1, acc[0][1]);
            acc[0][2] = fmaf(a0, b2, acc[0][2]); acc[0][3] = fmaf(a0, b3, acc[0][3]);
            acc[1][0] = fmaf(a1, b0, acc[1][0]); acc[1][1] = fmaf(a1, b1, acc[1][1]);
            acc[1][2] = fmaf(a1, b2, acc[1][2]); acc[1][3] = fmaf(a1, b3, acc[1][3]);
            acc[2][0] = fmaf(a2, b0, acc[2][0]); acc[2][1] = fmaf(a2, b1, acc[2][1]);
            acc[2][2] = fmaf(a2, b2, acc[2][2]); acc[2][3] = fmaf(a2, b3, acc[2][3]);
            acc[3][0] = fmaf(a3, b0, acc[3][0]); acc[3][1] = fmaf(a3, b1, acc[3][1]);
            acc[3][2] = fmaf(a3, b2, acc[3][2]); acc[3][3] = fmaf(a3, b3, acc[3][3]);
        }
        __syncthreads();
    }
#pragma unroll
    for (int i = 0; i < 4; i++) {
        int gr = rowBase + ty * 4 + i;
        if (gr < M) {
#pragma unroll
            for (int j = 0; j < 4; j++)
                C[(size_t)gr * N + colBase + tx * 4 + j] = acc[i][j];
        }
    }
}

// ---------------------------------------------------------------------------
// GCN aggregate: h[i] = relu(dinv[i]*(sum_j tmp[j]*dinv[j] + tmp[i]*dinv[i]) + b)
// one wave per node, lane = float4 of channels (64*4 = 256)
__global__ __launch_bounds__(256) void aggregate(const float* __restrict__ tmp,
                                                 float* __restrict__ out,
                                                 const int* __restrict__ col_ptr,
                                                 const int* __restrict__ adj,
                                                 const float* __restrict__ dinv,
                                                 const float* __restrict__ bias) {
    int wave = (blockIdx.x * blockDim.x + threadIdx.x) >> 6;
    int lane = threadIdx.x & 63;
    if (wave >= N_NODES) return;
    int i = wave;
    float di = dinv[i];
    float4 self = ((const float4*)(tmp + (size_t)i * CDIM))[lane];
    float4 acc;
    acc.x = self.x * di; acc.y = self.y * di; acc.z = self.z * di; acc.w = self.w * di;
    int s = col_ptr[i], e = col_ptr[i + 1];
    for (int idx = s; idx < e; idx++) {
        int j = adj[idx];
        float dj = dinv[j];
        float4 v = ((const float4*)(tmp + (size_t)j * CDIM))[lane];
        acc.x = fmaf(v.x, dj, acc.x); acc.y = fmaf(v.y, dj, acc.y);
        acc.z = fmaf(v.z, dj, acc.z); acc.w = fmaf(v.w, dj, acc.w);
    }
    float4 bv = ((const float4*)bias)[lane];
    float4 r;
    r.x = fmaxf(fmaf(acc.x, di, bv.x), 0.f);
    r.y = fmaxf(fmaf(acc.y, di, bv.y), 0.f);
    r.z = fmaxf(fmaf(acc.z, di, bv.z), 0.f);
    r.w = fmaxf(fmaf(acc.w, di, bv.w), 0.f);
    ((float4*)(out + (size_t)i * CDIM))[lane] = r;
}

// scatter-mean pool: graph[d] = mean over protein neighbors of h2
__global__ __launch_bounds__(256) void pool_drugs(const float* __restrict__ h2,
                                                  float* __restrict__ graph,
                                                  const int* __restrict__ drug_ptr,
                                                  const int* __restrict__ adj_drug) {
    int wave = (blockIdx.x * blockDim.x + threadIdx.x) >> 6;
    int lane = threadIdx.x & 63;
    if (wave >= NUM_DRUGS) return;
    int d = wave;
    int s = drug_ptr[d], e = drug_ptr[d + 1];
    float4 acc = make_float4(0.f, 0.f, 0.f, 0.f);
    for (int idx = s; idx < e; idx++) {
        int p = adj_drug[idx];
        float4 v = ((const float4*)(h2 + (size_t)p * CDIM))[lane];
        acc.x += v.x; acc.y += v.y; acc.z += v.z; acc.w += v.w;
    }
    int cnt = e - s;
    float sc = 1.f / (float)(cnt > 1 ? cnt : 1);
    acc.x *= sc; acc.y *= sc; acc.z *= sc; acc.w *= sc;
    ((float4*)(graph + (size_t)d * CDIM))[lane] = acc;
}

// init output with b2 bias of each row's expert
__global__ void out_init(float* __restrict__ outp, const int* __restrict__ ecl,
                         const float* __restrict__ b2) {
    int i = blockIdx.x * blockDim.x + threadIdx.x;
    if (i < BATCH) outp[i] = b2[ecl[i]];
}

// grouped-by-expert MLP: hid = relu(xcat@W1[e]+b1[e]); out += hid@W2[e]
// block = 64 rows x 64 hid-cols tile for one expert; K=512 (concat of two graph rows)
__global__ __launch_bounds__(256) void mlp_gemm(const float* __restrict__ graph,
                                                const int* __restrict__ ddb,
                                                const int* __restrict__ perm,
                                                const int* __restrict__ cloff,
                                                const float* __restrict__ W1,
                                                const float* __restrict__ b1,
                                                const float* __restrict__ W2,
                                                float* __restrict__ outp) {
    int e = blockIdx.z;
    int rt = blockIdx.y;
    int ct = blockIdx.x;
    int lo = cloff[e], hi = cloff[e + 1];
    int base = lo + rt * 64;
    if (base >= hi) return;
    __shared__ int rid[64];
    __shared__ int g0[64];
    __shared__ int g1[64];
    __shared__ float As[16][68];
    __shared__ float Bs[16][68];
    __shared__ float rowacc[64];
    int t = threadIdx.x;
    if (t < 64) {
        int idx = base + t;
        if (idx < hi) {
            int r = perm[idx];
            rid[t] = r;
            g0[t] = ddb[r] * CDIM;
            g1[t] = ddb[BATCH + r] * CDIM;
        } else {
            rid[t] = -1; g0[t] = 0; g1[t] = 0;
        }
        rowacc[t] = 0.f;
    }
    __syncthreads();
    const float* W1e = W1 + (size_t)e * HID * HID;   // [2*EMB=512, HID=512] row-major
    int tx = t & 15, ty = t >> 4;
    int ar = t >> 2, ak = (t & 3) * 4;
    int bk = t >> 4, bn = (t & 15) * 4;
    int colBase = ct * 64;
    float acc[4][4] = {};
    for (int kk = 0; kk < 2 * CDIM; kk += 16) {
        float4 av = make_float4(0.f, 0.f, 0.f, 0.f);
        if (rid[ar] >= 0) {
            int k = kk + ak;
            const float* src = (k < CDIM) ? (graph + g0[ar] + k)
                                          : (graph + g1[ar] + (k - CDIM));
            av = *(const float4*)src;
        }
        As[ak + 0][ar] = av.x; As[ak + 1][ar] = av.y;
        As[ak + 2][ar] = av.z; As[ak + 3][ar] = av.w;
        *(float4*)&Bs[bk][bn] = *(const float4*)(W1e + (size_t)(kk + bk) * HID + colBase + bn);
        __syncthreads();
#pragma unroll
        for (int k = 0; k < 16; k++) {
            float a0 = As[k][ty * 4 + 0], a1 = As[k][ty * 4 + 1];
            float a2 = As[k][ty * 4 + 2], a3 = As[k][ty * 4 + 3];
            float b0 = Bs[k][tx * 4 + 0], b1v = Bs[k][tx * 4 + 1];
            float b2v = Bs[k][tx * 4 + 2], b3 = Bs[k][tx * 4 + 3];
            acc[0][0] = fmaf(a0, b0, acc[0][0]); acc[0][1] = fmaf(a0, b1v, acc[0][1]);
            acc[0][2] = fmaf(a0, b2v, acc[0][2]); acc[0][3] = fmaf(a0, b3, acc[0][3]);
            acc[1][0] = fmaf(a1, b0, acc[1][0]); acc[1][1] = fmaf(a1, b1v, acc[1][1]);
            acc[1][2] = fmaf(a1, b2v, acc[1][2]); acc[1][3] = fmaf(a1, b3, acc[1][3]);
            acc[2][0] = fmaf(a2, b0, acc[2][0]); acc[2][1] = fmaf(a2, b1v, acc[2][1]);
            acc[2][2] = fmaf(a2, b2v, acc[2][2]); acc[2][3] = fmaf(a2, b3, acc[2][3]);
            acc[3][0] = fmaf(a3, b0, acc[3][0]); acc[3][1] = fmaf(a3, b1v, acc[3][1]);
            acc[3][2] = fmaf(a3, b2v, acc[3][2]); acc[3][3] = fmaf(a3, b3, acc[3][3]);
        }
        __syncthreads();
    }
    // epilogue: relu + b1, dot with W2 column, row-reduce, atomic to out
    const float* b1e = b1 + (size_t)e * HID;
    const float* W2e = W2 + (size_t)e * HID;   // [HID, 1]
    float part[4] = {0.f, 0.f, 0.f, 0.f};
#pragma unroll
    for (int j = 0; j < 4; j++) {
        int c = colBase + tx * 4 + j;
        float bb = b1e[c], w2 = W2e[c];
#pragma unroll
        for (int i = 0; i < 4; i++) {
            float h = fmaxf(acc[i][j] + bb, 0.f);
            part[i] = fmaf(h, w2, part[i]);
        }
    }
#pragma unroll
    for (int i = 0; i < 4; i++) atomicAdd(&rowacc[ty * 4 + i], part[i]);
    __syncthreads();
    if (t < 64 && rid[t] >= 0) atomicAdd(&outp[rid[t]], rowacc[t]);
}

// ---------------------------------------------------------------------------
extern "C" void kernel_launch(void* const* d_in, const int* in_sizes, int n_in,
                              void* d_out, int out_size, void* d_ws, size_t ws_size,
                              hipStream_t stream) {
    const float* x   = (const float*)d_in[0];
    const int* ei    = (const int*)d_in[1];     // [2, 400000] flat
    const int* ddb   = (const int*)d_in[2];     // [2, 16384] flat
    const int* ecl   = (const int*)d_in[3];     // [16384]
    const float* Wg1 = (const float*)d_in[5];
    const float* bg1 = (const float*)d_in[6];
    const float* Wg2 = (const float*)d_in[7];
    const float* bg2 = (const float*)d_in[8];
    const float* W1  = (const float*)d_in[9];
    const float* b1  = (const float*)d_in[10];
    const float* W2  = (const float*)d_in[11];
    const float* b2  = (const float*)d_in[12];
    float* outp = (float*)d_out;

    // workspace carve-up (16B aligned)
    char* p = (char*)d_ws;
    auto alloc = [&](size_t bytes) {
        char* r = p;
        p += (bytes + 15) & ~size_t(15);
        return (void*)r;
    };
    float* bufA   = (float*)alloc(sizeof(float) * N_NODES * CDIM);
    float* bufB   = (float*)alloc(sizeof(float) * N_NODES * CDIM);
    float* graph  = (float*)alloc(sizeof(float) * NUM_DRUGS * CDIM);
    float* dinv   = (float*)alloc(sizeof(float) * N_NODES);
    int* cnt_col  = (int*)alloc(sizeof(int) * N_NODES);
    int* col_ptr  = (int*)alloc(sizeof(int) * (N_NODES + 1));
    int* cur_col  = (int*)alloc(sizeof(int) * N_NODES);
    int* adj_col  = (int*)alloc(sizeof(int) * E2);
    int* cnt_drug = (int*)alloc(sizeof(int) * NUM_DRUGS);
    int* drug_ptr = (int*)alloc(sizeof(int) * (NUM_DRUGS + 1));
    int* cur_drug = (int*)alloc(sizeof(int) * NUM_DRUGS);
    int* adj_drug = (int*)alloc(sizeof(int) * NUM_DPI);
    int* clcnt    = (int*)alloc(sizeof(int) * N_CL);
    int* cloff    = (int*)alloc(sizeof(int) * (N_CL + 1));
    int* curcl    = (int*)alloc(sizeof(int) * N_CL);
    int* perm     = (int*)alloc(sizeof(int) * BATCH);

    // 1. zero counters
    zero_counts<<<(N_NODES + 255) / 256, 256, 0, stream>>>(cnt_col, cur_col, cnt_drug,
                                                           cur_drug, clcnt, curcl);
    // 2. counts
    count_all<<<(E2 + 255) / 256, 256, 0, stream>>>(ei, ecl, cnt_col, cnt_drug, clcnt);
    // 3. scans
    scan_block<<<1, 1024, 0, stream>>>(cnt_col, col_ptr, N_NODES);
    scan_block<<<1, 1024, 0, stream>>>(cnt_drug, drug_ptr, NUM_DRUGS);
    scan_block<<<1, 1024, 0, stream>>>(clcnt, cloff, N_CL);
    // 4. fill CSR lists + perm + dinv
    fill_all<<<(E2 + 255) / 256, 256, 0, stream>>>(ei, ecl, col_ptr, cur_col, adj_col,
                                                   drug_ptr, cur_drug, adj_drug,
                                                   cloff, curcl, perm, cnt_col, dinv);
    // 5. GCN layer 1
    gemm64<<<dim3((N_NODES + 63) / 64, CDIM / 64), 256, 0, stream>>>(x, Wg1, bufA,
                                                                     N_NODES, CDIM, CDIM);
    aggregate<<<(N_NODES * 64 + 255) / 256, 256, 0, stream>>>(bufA, bufB, col_ptr,
                                                              adj_col, dinv, bg1);
    // 6. GCN layer 2
    gemm64<<<dim3((N_NODES + 63) / 64, CDIM / 64), 256, 0, stream>>>(bufB, Wg2, bufA,
                                                                     N_NODES, CDIM, CDIM);
    aggregate<<<(N_NODES * 64 + 255) / 256, 256, 0, stream>>>(bufA, bufB, col_ptr,
                                                              adj_col, dinv, bg2);
    // 7. pool proteins -> drug graph embeddings
    pool_drugs<<<(NUM_DRUGS * 64 + 255) / 256, 256, 0, stream>>>(bufB, graph,
                                                                 drug_ptr, adj_drug);
    // 8. MLP: init out with b2, then grouped expert GEMM with fused layer 2
    out_init<<<(BATCH + 255) / 256, 256, 0, stream>>>(outp, ecl, b2);
    mlp_gemm<<<dim3(HID / 64, (BATCH + 63) / 64, N_CL), 256, 0, stream>>>(
        graph, ddb, perm, cloff, W1, b1, W2, outp);
}

// Round 2
// 630.395 us; speedup vs baseline: 1.1695x; 1.1695x over previous
//
#include <hip/hip_runtime.h>
#include <hip/hip_bf16.h>

// Problem constants (fixed by reference)
#define N_NODES 20000
#define NUM_DRUGS 2048
#define NUM_DPI 200000
#define E2 400000          // 2*NUM_DPI directed edges
#define CDIM 256           // IN_C == EMB == 256
#define HID 512
#define N_CL 8
#define BATCH 16384

typedef __attribute__((ext_vector_type(8))) short short8;   // 8 bf16 = 4 VGPR (MFMA A/B frag)
typedef __attribute__((ext_vector_type(4))) float floatx4;  // MFMA C/D frag

__device__ inline unsigned short f2bf(float f) {
    unsigned u = __float_as_uint(f);
    u += 0x7fff + ((u >> 16) & 1);   // RNE
    return (unsigned short)(u >> 16);
}
__device__ inline float bf2f(unsigned short h) {
    return __uint_as_float((unsigned)h << 16);
}
__device__ inline void split2(float v, unsigned short& h, unsigned short& l) {
    h = f2bf(v);
    l = f2bf(v - bf2f(h));
}
__device__ inline void gload16(const void* g, void* l) {
    __builtin_amdgcn_global_load_lds(
        (const __attribute__((address_space(1))) void*)g,
        (__attribute__((address_space(3))) void*)l, 16, 0, 0);
}

// ---------------------------------------------------------------------------
__global__ void zero_counts(int* cnt_col, int* cur_col, int* cnt_drug, int* cur_drug,
                            int* clcnt, int* curcl) {
    int i = blockIdx.x * blockDim.x + threadIdx.x;
    if (i < N_NODES) { cnt_col[i] = 0; cur_col[i] = 0; }
    if (i < NUM_DRUGS) { cnt_drug[i] = 0; cur_drug[i] = 0; }
    if (i < N_CL) { clcnt[i] = 0; curcl[i] = 0; }
}

__global__ void count_all(const int* __restrict__ ei, const int* __restrict__ ecl,
                          int* cnt_col, int* cnt_drug, int* clcnt) {
    int e = blockIdx.x * blockDim.x + threadIdx.x;
    if (e < E2) atomicAdd(&cnt_col[ei[E2 + e]], 1);
    if (e < NUM_DPI) atomicAdd(&cnt_drug[ei[e]], 1);
    if (e < BATCH) atomicAdd(&clcnt[ecl[e]], 1);
}

__global__ void scan_block(const int* __restrict__ counts, int* __restrict__ ptr, int n) {
    __shared__ int sums[1024];
    int t = threadIdx.x;
    int per = (n + 1023) / 1024;
    int start = t * per;
    int end = start + per; if (end > n) end = n;
    int s = 0;
    for (int i = start; i < end; i++) s += counts[i];
    sums[t] = s;
    __syncthreads();
    for (int off = 1; off < 1024; off <<= 1) {
        int v = (t >= off) ? sums[t - off] : 0;
        __syncthreads();
        sums[t] += v;
        __syncthreads();
    }
    int base = (t == 0) ? 0 : sums[t - 1];
    for (int i = start; i < end; i++) {
        ptr[i] = base;
        base += counts[i];
    }
    if (t == 1023) ptr[n] = sums[1023];
}

__global__ void fill_all(const int* __restrict__ ei, const int* __restrict__ ecl,
                         const int* __restrict__ col_ptr, int* cur_col, int* adj_col,
                         const int* __restrict__ drug_ptr, int* cur_drug, int* adj_drug,
                         const int* __restrict__ cloff, int* curcl, int* perm,
                         const int* __restrict__ cnt_col, float* dinv) {
    int e = blockIdx.x * blockDim.x + threadIdx.x;
    if (e < E2) {
        int c = ei[E2 + e];
        int pos = col_ptr[c] + atomicAdd(&cur_col[c], 1);
        adj_col[pos] = ei[e];
    }
    if (e < NUM_DPI) {
        int d = ei[e];
        int pos = drug_ptr[d] + atomicAdd(&cur_drug[d], 1);
        adj_drug[pos] = ei[E2 + e];
    }
    if (e < BATCH) {
        int c = ecl[e];
        int pos = cloff[c] + atomicAdd(&curcl[c], 1);
        perm[pos] = e;
    }
    if (e < N_NODES) {
        dinv[e] = rsqrtf((float)(cnt_col[e] + 1));
    }
}

// ---------------------------------------------------------------------------
// fp32 -> (hi,lo) bf16 split, elementwise
__global__ void split_mat(const float* __restrict__ A, unsigned short* __restrict__ hi,
                          unsigned short* __restrict__ lo, int total) {
    int i = blockIdx.x * blockDim.x + threadIdx.x;
    if (i >= total) return;
    unsigned short h, l;
    split2(A[i], h, l);
    hi[i] = h; lo[i] = l;
}

// W [m][K][N] fp32 -> WT [m][N][K] split bf16 (coalesced writes along k)
__global__ void transpose_split(const float* __restrict__ W, unsigned short* __restrict__ hi,
                                unsigned short* __restrict__ lo, int K, int N, int total) {
    int idx = blockIdx.x * blockDim.x + threadIdx.x;
    if (idx >= total) return;
    int per = K * N;
    int m = idx / per, rem = idx - m * per;
    int n = rem / K, k = rem - n * K;
    float v = W[(size_t)m * per + (size_t)k * N + n];
    unsigned short h, l;
    split2(v, h, l);
    hi[idx] = h; lo[idx] = l;
}

// ---------------------------------------------------------------------------
// split-bf16 MFMA GEMM: C[M,N] = A[M,K] @ B[K,N], A given split row-major,
// B given as B^T split row-major ([N][K]). 128x128 tile, 256 thr (4 waves).
__global__ __launch_bounds__(256) void gemm_mfma(
        const unsigned short* __restrict__ Ahi, const unsigned short* __restrict__ Alo,
        const unsigned short* __restrict__ BThi, const unsigned short* __restrict__ BTlo,
        float* __restrict__ C, int M, int K, int N) {
    __shared__ unsigned short sAh[4096], sAl[4096], sBh[4096], sBl[4096];
    int t = threadIdx.x;
    int wv = t >> 6, lane = t & 63, quad = lane >> 4, l15 = lane & 15;
    int m0 = blockIdx.x * 128, n0 = blockIdx.y * 128;
    int m0w = (wv >> 1) * 64, n0w = (wv & 1) * 64;
    int srow = t >> 2;
    int skoff = (t & 3) * 8;
    floatx4 zero = {0.f, 0.f, 0.f, 0.f};
    floatx4 acc[4][4];
#pragma unroll
    for (int i = 0; i < 4; i++)
#pragma unroll
        for (int j = 0; j < 4; j++) acc[i][j] = zero;

    for (int kk = 0; kk < K; kk += 32) {
#pragma unroll
        for (int c = 0; c < 2; c++) {
            int arow = m0 + srow + c * 64; if (arow > M - 1) arow = M - 1;
            int brow = n0 + srow + c * 64; if (brow > N - 1) brow = N - 1;
            size_t aoff = (size_t)arow * K + kk + skoff;
            size_t boff = (size_t)brow * K + kk + skoff;
            int loff = (t + c * 256) * 8;
            gload16(Ahi + aoff, &sAh[loff]);
            gload16(Alo + aoff, &sAl[loff]);
            gload16(BThi + boff, &sBh[loff]);
            gload16(BTlo + boff, &sBl[loff]);
        }
        __syncthreads();
        short8 ah[4], al[4], bh[4], bl[4];
#pragma unroll
        for (int i = 0; i < 4; i++) {
            int r = (m0w + i * 16 + l15) * 32 + quad * 8;
            ah[i] = *(const short8*)&sAh[r];
            al[i] = *(const short8*)&sAl[r];
        }
#pragma unroll
        for (int j = 0; j < 4; j++) {
            int r = (n0w + j * 16 + l15) * 32 + quad * 8;
            bh[j] = *(const short8*)&sBh[r];
            bl[j] = *(const short8*)&sBl[r];
        }
#pragma unroll
        for (int i = 0; i < 4; i++)
#pragma unroll
            for (int j = 0; j < 4; j++) {
                acc[i][j] = __builtin_amdgcn_mfma_f32_16x16x32_bf16(ah[i], bh[j], acc[i][j], 0, 0, 0);
                acc[i][j] = __builtin_amdgcn_mfma_f32_16x16x32_bf16(ah[i], bl[j], acc[i][j], 0, 0, 0);
                acc[i][j] = __builtin_amdgcn_mfma_f32_16x16x32_bf16(al[i], bh[j], acc[i][j], 0, 0, 0);
            }
        __syncthreads();
    }
#pragma unroll
    for (int i = 0; i < 4; i++) {
        int gr = m0 + m0w + i * 16 + quad * 4;
#pragma unroll
        for (int r = 0; r < 4; r++) {
            if (gr + r < M) {
#pragma unroll
                for (int j = 0; j < 4; j++)
                    C[(size_t)(gr + r) * N + n0 + n0w + j * 16 + l15] = acc[i][j][r];
            }
        }
    }
}

// ---------------------------------------------------------------------------
// GCN aggregate, optionally emitting split-bf16 (for next GEMM) or fp32
__global__ __launch_bounds__(256) void aggregate_k(const float* __restrict__ tmp,
                                                   const int* __restrict__ col_ptr,
                                                   const int* __restrict__ adj,
                                                   const float* __restrict__ dinv,
                                                   const float* __restrict__ bias,
                                                   float* __restrict__ outf,
                                                   unsigned short* __restrict__ outhi,
                                                   unsigned short* __restrict__ outlo) {
    int wave = (blockIdx.x * blockDim.x + threadIdx.x) >> 6;
    int lane = threadIdx.x & 63;
    if (wave >= N_NODES) return;
    int i = wave;
    float di = dinv[i];
    float4 self = ((const float4*)(tmp + (size_t)i * CDIM))[lane];
    float4 acc;
    acc.x = self.x * di; acc.y = self.y * di; acc.z = self.z * di; acc.w = self.w * di;
    int s = col_ptr[i], e = col_ptr[i + 1];
    for (int idx = s; idx < e; idx++) {
        int j = adj[idx];
        float dj = dinv[j];
        float4 v = ((const float4*)(tmp + (size_t)j * CDIM))[lane];
        acc.x = fmaf(v.x, dj, acc.x); acc.y = fmaf(v.y, dj, acc.y);
        acc.z = fmaf(v.z, dj, acc.z); acc.w = fmaf(v.w, dj, acc.w);
    }
    float4 bv = ((const float4*)bias)[lane];
    float4 r;
    r.x = fmaxf(fmaf(acc.x, di, bv.x), 0.f);
    r.y = fmaxf(fmaf(acc.y, di, bv.y), 0.f);
    r.z = fmaxf(fmaf(acc.z, di, bv.z), 0.f);
    r.w = fmaxf(fmaf(acc.w, di, bv.w), 0.f);
    if (outhi) {
        ushort4 h, l;
        split2(r.x, h.x, l.x); split2(r.y, h.y, l.y);
        split2(r.z, h.z, l.z); split2(r.w, h.w, l.w);
        *(ushort4*)&outhi[(size_t)i * CDIM + lane * 4] = h;
        *(ushort4*)&outlo[(size_t)i * CDIM + lane * 4] = l;
    } else {
        ((float4*)(outf + (size_t)i * CDIM))[lane] = r;
    }
}

// scatter-mean pool -> split-bf16 graph embeddings
__global__ __launch_bounds__(256) void pool_drugs(const float* __restrict__ h2,
                                                  unsigned short* __restrict__ Ghi,
                                                  unsigned short* __restrict__ Glo,
                                                  const int* __restrict__ drug_ptr,
                                                  const int* __restrict__ adj_drug) {
    int wave = (blockIdx.x * blockDim.x + threadIdx.x) >> 6;
    int lane = threadIdx.x & 63;
    if (wave >= NUM_DRUGS) return;
    int d = wave;
    int s = drug_ptr[d], e = drug_ptr[d + 1];
    float4 acc = make_float4(0.f, 0.f, 0.f, 0.f);
    for (int idx = s; idx < e; idx++) {
        int p = adj_drug[idx];
        float4 v = ((const float4*)(h2 + (size_t)p * CDIM))[lane];
        acc.x += v.x; acc.y += v.y; acc.z += v.z; acc.w += v.w;
    }
    int cnt = e - s;
    float sc = 1.f / (float)(cnt > 1 ? cnt : 1);
    acc.x *= sc; acc.y *= sc; acc.z *= sc; acc.w *= sc;
    ushort4 h, l;
    split2(acc.x, h.x, l.x); split2(acc.y, h.y, l.y);
    split2(acc.z, h.z, l.z); split2(acc.w, h.w, l.w);
    *(ushort4*)&Ghi[(size_t)d * CDIM + lane * 4] = h;
    *(ushort4*)&Glo[(size_t)d * CDIM + lane * 4] = l;
}

__global__ void out_init(float* __restrict__ outp, const int* __restrict__ ecl,
                         const float* __restrict__ b2) {
    int i = blockIdx.x * blockDim.x + threadIdx.x;
    if (i < BATCH) outp[i] = b2[ecl[i]];
}

// ---------------------------------------------------------------------------
// grouped MoE MLP via split-bf16 MFMA; A rows gathered via perm/ddb (concat K=512),
// fused relu+b1 and the [512,1] second layer in the epilogue.
__global__ __launch_bounds__(256) void mlp_mfma(
        const unsigned short* __restrict__ Ghi, const unsigned short* __restrict__ Glo,
        const unsigned short* __restrict__ W1Thi, const unsigned short* __restrict__ W1Tlo,
        const float* __restrict__ b1, const float* __restrict__ W2,
        const int* __restrict__ ddb, const int* __restrict__ perm,
        const int* __restrict__ cloff, float* __restrict__ outp) {
    int e = blockIdx.z;
    int lo_ = cloff[e], hi_ = cloff[e + 1];
    int base = lo_ + blockIdx.y * 128;
    if (base >= hi_) return;
    __shared__ unsigned short sAh[4096], sAl[4096], sBh[4096], sBl[4096];
    __shared__ int rid[128], g0s[128], g1s[128];
    int t = threadIdx.x;
    if (t < 128) {
        int idx = base + t;
        if (idx < hi_) {
            int r = perm[idx];
            rid[t] = r;
            g0s[t] = ddb[r] * CDIM;
            g1s[t] = ddb[BATCH + r] * CDIM;
        } else {
            rid[t] = -1; g0s[t] = 0; g1s[t] = 0;
        }
    }
    __syncthreads();
    int wv = t >> 6, lane = t & 63, quad = lane >> 4, l15 = lane & 15;
    int n0 = blockIdx.x * 128;
    int m0w = (wv >> 1) * 64, n0w = (wv & 1) * 64;
    int srow = t >> 2;
    int skoff = (t & 3) * 8;
    const unsigned short* W1eh = W1Thi + (size_t)e * HID * HID;
    const unsigned short* W1el = W1Tlo + (size_t)e * HID * HID;
    floatx4 zero = {0.f, 0.f, 0.f, 0.f};
    floatx4 acc[4][4];
#pragma unroll
    for (int i = 0; i < 4; i++)
#pragma unroll
        for (int j = 0; j < 4; j++) acc[i][j] = zero;

    for (int kk = 0; kk < 2 * CDIM; kk += 32) {
        const int* gsel = (kk < CDIM) ? g0s : g1s;
        int kbase = kk & (CDIM - 1);
#pragma unroll
        for (int c = 0; c < 2; c++) {
            int arow = srow + c * 64;
            size_t aoff = (size_t)gsel[arow] + kbase + skoff;
            size_t boff = (size_t)(n0 + srow + c * 64) * HID + kk + skoff;
            int loff = (t + c * 256) * 8;
            gload16(Ghi + aoff, &sAh[loff]);
            gload16(Glo + aoff, &sAl[loff]);
            gload16(W1eh + boff, &sBh[loff]);
            gload16(W1el + boff, &sBl[loff]);
        }
        __syncthreads();
        short8 ah[4], al[4], bh[4], bl[4];
#pragma unroll
        for (int i = 0; i < 4; i++) {
            int r = (m0w + i * 16 + l15) * 32 + quad * 8;
            ah[i] = *(const short8*)&sAh[r];
            al[i] = *(const short8*)&sAl[r];
        }
#pragma unroll
        for (int j = 0; j < 4; j++) {
            int r = (n0w + j * 16 + l15) * 32 + quad * 8;
            bh[j] = *(const short8*)&sBh[r];
            bl[j] = *(const short8*)&sBl[r];
        }
#pragma unroll
        for (int i = 0; i < 4; i++)
#pragma unroll
            for (int j = 0; j < 4; j++) {
                acc[i][j] = __builtin_amdgcn_mfma_f32_16x16x32_bf16(ah[i], bh[j], acc[i][j], 0, 0, 0);
                acc[i][j] = __builtin_amdgcn_mfma_f32_16x16x32_bf16(ah[i], bl[j], acc[i][j], 0, 0, 0);
                acc[i][j] = __builtin_amdgcn_mfma_f32_16x16x32_bf16(al[i], bh[j], acc[i][j], 0, 0, 0);
            }
        __syncthreads();
    }
    // epilogue: relu(acc + b1) dot W2 over this block's 128 cols, reduce, atomic add
    const float* b1e = b1 + (size_t)e * HID;
    const float* W2e = W2 + (size_t)e * HID;
#pragma unroll
    for (int i = 0; i < 4; i++) {
#pragma unroll
        for (int r = 0; r < 4; r++) {
            float s = 0.f;
#pragma unroll
            for (int j = 0; j < 4; j++) {
                int col = n0 + n0w + j * 16 + l15;
                float h = fmaxf(acc[i][j][r] + b1e[col], 0.f);
                s = fmaf(h, W2e[col], s);
            }
            s += __shfl_xor(s, 1, 16);
            s += __shfl_xor(s, 2, 16);
            s += __shfl_xor(s, 4, 16);
            s += __shfl_xor(s, 8, 16);
            if (l15 == 0) {
                int rowl = m0w + i * 16 + quad * 4 + r;
                int rr = rid[rowl];
                if (rr >= 0) atomicAdd(&outp[rr], s);
            }
        }
    }
}

// ---------------------------------------------------------------------------
extern "C" void kernel_launch(void* const* d_in, const int* in_sizes, int n_in,
                              void* d_out, int out_size, void* d_ws, size_t ws_size,
                              hipStream_t stream) {
    const float* x   = (const float*)d_in[0];
    const int* ei    = (const int*)d_in[1];
    const int* ddb   = (const int*)d_in[2];
    const int* ecl   = (const int*)d_in[3];
    const float* Wg1 = (const float*)d_in[5];
    const float* bg1 = (const float*)d_in[6];
    const float* Wg2 = (const float*)d_in[7];
    const float* bg2 = (const float*)d_in[8];
    const float* W1  = (const float*)d_in[9];
    const float* b1  = (const float*)d_in[10];
    const float* W2  = (const float*)d_in[11];
    const float* b2  = (const float*)d_in[12];
    float* outp = (float*)d_out;

    char* p = (char*)d_ws;
    auto alloc = [&](size_t bytes) {
        char* r = p;
        p += (bytes + 255) & ~size_t(255);
        return (void*)r;
    };
    const size_t NC = (size_t)N_NODES * CDIM;
    float* tmp            = (float*)alloc(sizeof(float) * NC);          // GEMM out
    unsigned short* h1hi  = (unsigned short*)alloc(2 * NC);
    unsigned short* h1lo  = (unsigned short*)alloc(2 * NC);
    char* xh2_blk         = (char*)alloc(4 * NC);                       // xhi+xlo, later h2
    unsigned short* xhi   = (unsigned short*)xh2_blk;
    unsigned short* xlo   = (unsigned short*)(xh2_blk + 2 * NC);
    float* h2             = (float*)xh2_blk;
    unsigned short* Ghi   = (unsigned short*)alloc(2 * NUM_DRUGS * CDIM);
    unsigned short* Glo   = (unsigned short*)alloc(2 * NUM_DRUGS * CDIM);
    unsigned short* wg1Th = (unsigned short*)alloc(2 * CDIM * CDIM);
    unsigned short* wg1Tl = (unsigned short*)alloc(2 * CDIM * CDIM);
    unsigned short* wg2Th = (unsigned short*)alloc(2 * CDIM * CDIM);
    unsigned short* wg2Tl = (unsigned short*)alloc(2 * CDIM * CDIM);
    unsigned short* W1Th  = (unsigned short*)alloc(2 * (size_t)N_CL * HID * HID);
    unsigned short* W1Tl  = (unsigned short*)alloc(2 * (size_t)N_CL * HID * HID);
    float* dinv   = (float*)alloc(sizeof(float) * N_NODES);
    int* cnt_col  = (int*)alloc(sizeof(int) * N_NODES);
    int* col_ptr  = (int*)alloc(sizeof(int) * (N_NODES + 1));
    int* cur_col  = (int*)alloc(sizeof(int) * N_NODES);
    int* adj_col  = (int*)alloc(sizeof(int) * E2);
    int* cnt_drug = (int*)alloc(sizeof(int) * NUM_DRUGS);
    int* drug_ptr = (int*)alloc(sizeof(int) * (NUM_DRUGS + 1));
    int* cur_drug = (int*)alloc(sizeof(int) * NUM_DRUGS);
    int* adj_drug = (int*)alloc(sizeof(int) * NUM_DPI);
    int* clcnt    = (int*)alloc(sizeof(int) * N_CL);
    int* cloff    = (int*)alloc(sizeof(int) * (N_CL + 1));
    int* curcl    = (int*)alloc(sizeof(int) * N_CL);
    int* perm     = (int*)alloc(sizeof(int) * BATCH);

    // graph prep
    zero_counts<<<(N_NODES + 255) / 256, 256, 0, stream>>>(cnt_col, cur_col, cnt_drug,
                                                           cur_drug, clcnt, curcl);
    count_all<<<(E2 + 255) / 256, 256, 0, stream>>>(ei, ecl, cnt_col, cnt_drug, clcnt);
    scan_block<<<1, 1024, 0, stream>>>(cnt_col, col_ptr, N_NODES);
    scan_block<<<1, 1024, 0, stream>>>(cnt_drug, drug_ptr, NUM_DRUGS);
    scan_block<<<1, 1024, 0, stream>>>(clcnt, cloff, N_CL);
    fill_all<<<(E2 + 255) / 256, 256, 0, stream>>>(ei, ecl, col_ptr, cur_col, adj_col,
                                                   drug_ptr, cur_drug, adj_drug,
                                                   cloff, curcl, perm, cnt_col, dinv);
    // weight/activation splits
    split_mat<<<((int)NC + 255) / 256, 256, 0, stream>>>(x, xhi, xlo, (int)NC);
    transpose_split<<<(CDIM * CDIM + 255) / 256, 256, 0, stream>>>(Wg1, wg1Th, wg1Tl,
                                                                   CDIM, CDIM, CDIM * CDIM);
    transpose_split<<<(CDIM * CDIM + 255) / 256, 256, 0, stream>>>(Wg2, wg2Th, wg2Tl,
                                                                   CDIM, CDIM, CDIM * CDIM);
    transpose_split<<<(N_CL * HID * HID + 255) / 256, 256, 0, stream>>>(
        W1, W1Th, W1Tl, HID, HID, N_CL * HID * HID);
    // GCN layer 1
    gemm_mfma<<<dim3((N_NODES + 127) / 128, CDIM / 128), 256, 0, stream>>>(
        xhi, xlo, wg1Th, wg1Tl, tmp, N_NODES, CDIM, CDIM);
    aggregate_k<<<(N_NODES * 64 + 255) / 256, 256, 0, stream>>>(
        tmp, col_ptr, adj_col, dinv, bg1, nullptr, h1hi, h1lo);
    // GCN layer 2
    gemm_mfma<<<dim3((N_NODES + 127) / 128, CDIM / 128), 256, 0, stream>>>(
        h1hi, h1lo, wg2Th, wg2Tl, tmp, N_NODES, CDIM, CDIM);
    aggregate_k<<<(N_NODES * 64 + 255) / 256, 256, 0, stream>>>(
        tmp, col_ptr, adj_col, dinv, bg2, h2, nullptr, nullptr);
    // pool -> split graph embeddings
    pool_drugs<<<(NUM_DRUGS * 64 + 255) / 256, 256, 0, stream>>>(h2, Ghi, Glo,
                                                                 drug_ptr, adj_drug);
    // MoE MLP
    out_init<<<(BATCH + 255) / 256, 256, 0, stream>>>(outp, ecl, b2);
    mlp_mfma<<<dim3(HID / 128, 24, N_CL), 256, 0, stream>>>(
        Ghi, Glo, W1Th, W1Tl, b1, W2, ddb, perm, cloff, outp);
}

// Round 3
// 495.363 us; speedup vs baseline: 1.4883x; 1.2726x over previous
//
#include <hip/hip_runtime.h>
#include <hip/hip_bf16.h>

// Problem constants (fixed by reference)
#define N_NODES 20000
#define NUM_DRUGS 2048
#define NUM_DPI 200000
#define E2 400000          // 2*NUM_DPI directed edges
#define CDIM 256           // IN_C == EMB == 256
#define HID 512
#define N_CL 8
#define BATCH 16384

#define STRD 32            // drug/cl counter padding (ints) = 1 line per counter
#define STRP 16            // protein counter padding

typedef __attribute__((ext_vector_type(8))) short short8;   // 8 bf16 (MFMA A/B frag)
typedef __attribute__((ext_vector_type(4))) float floatx4;  // MFMA C/D frag

__device__ inline unsigned short f2bf(float f) {
    unsigned u = __float_as_uint(f);
    u += 0x7fff + ((u >> 16) & 1);   // RNE
    return (unsigned short)(u >> 16);
}
__device__ inline float bf2f(unsigned short h) {
    return __uint_as_float((unsigned)h << 16);
}
__device__ inline void split2(float v, unsigned short& h, unsigned short& l) {
    h = f2bf(v);
    l = f2bf(v - bf2f(h));
}
__device__ inline void gload16(const void* g, void* l) {
    __builtin_amdgcn_global_load_lds(
        (const __attribute__((address_space(1))) void*)g,
        (__attribute__((address_space(3))) void*)l, 16, 0, 0);
}

// ---------------------------------------------------------------------------
__global__ void zero_counts(int* cnt_d, int* cur_d, int* cnt_p, int* cur_p,
                            int* clcnt, int* curcl) {
    int i = blockIdx.x * blockDim.x + threadIdx.x;
    if (i < N_NODES) { cnt_p[i * STRP] = 0; cur_p[i * STRP] = 0; }
    if (i < NUM_DRUGS) { cnt_d[i * STRD] = 0; cur_d[i * STRD] = 0; }
    if (i < N_CL) { clcnt[i * STRD] = 0; curcl[i * STRD] = 0; }
}

// count DPI pairs into padded per-drug / per-protein histograms
__global__ void count_dpi(const int* __restrict__ ei, int* cnt_d, int* cnt_p) {
    int e = blockIdx.x * blockDim.x + threadIdx.x;
    if (e >= NUM_DPI) return;
    atomicAdd(&cnt_d[ei[e] * STRD], 1);          // drug id of pair e
    atomicAdd(&cnt_p[ei[E2 + e] * STRP], 1);     // protein id of pair e
}

// cell-line histogram via block-local LDS bins (16K atomics -> 512)
__global__ void count_cl(const int* __restrict__ ecl, int* clcnt) {
    __shared__ int lh[N_CL];
    int t = threadIdx.x;
    int r = blockIdx.x * 256 + t;
    if (t < N_CL) lh[t] = 0;
    __syncthreads();
    atomicAdd(&lh[ecl[r]], 1);
    __syncthreads();
    if (t < N_CL && lh[t] > 0) atomicAdd(&clcnt[t * STRD], lh[t]);
}

// generic strided single-block exclusive scan
__device__ void scan_dev(const int* counts, int stride, int* ptr, int n) {
    __shared__ int sums[1024];
    int t = threadIdx.x;
    int per = (n + 1023) / 1024;
    int start = t * per;
    int end = start + per; if (end > n) end = n;
    int s = 0;
    for (int i = start; i < end; i++) s += counts[i * stride];
    sums[t] = s;
    __syncthreads();
    for (int off = 1; off < 1024; off <<= 1) {
        int v = (t >= off) ? sums[t - off] : 0;
        __syncthreads();
        sums[t] += v;
        __syncthreads();
    }
    int base = (t == 0) ? 0 : sums[t - 1];
    for (int i = start; i < end; i++) {
        ptr[i] = base;
        base += counts[i * stride];
    }
    if (t == 1023) ptr[n] = sums[1023];
}

__global__ void scan3(const int* cnt_d, const int* cnt_p, const int* clcnt,
                      int* drug_ptr, int* prot_ptr, int* cloff) {
    if (blockIdx.x == 0) scan_dev(cnt_d, STRD, drug_ptr, NUM_DRUGS);
    else if (blockIdx.x == 1) scan_dev(cnt_p, STRP, prot_ptr, N_NODES);
    else scan_dev(clcnt, STRD, cloff, N_CL);
}

// fill both adjacency lists from DPI pairs; padded counters kill line ping-pong
__global__ void fill_dpi(const int* __restrict__ ei,
                         const int* __restrict__ drug_ptr, int* cur_d, int* adj_drug,
                         const int* __restrict__ prot_ptr, int* cur_p, int* adj_prot,
                         float* __restrict__ dinv) {
    int e = blockIdx.x * blockDim.x + threadIdx.x;
    if (e < NUM_DPI) {
        int d = ei[e];
        int p = ei[E2 + e];
        int posd = drug_ptr[d] + atomicAdd(&cur_d[d * STRD], 1);
        int posp = prot_ptr[p] + atomicAdd(&cur_p[p * STRP], 1);
        adj_drug[posd] = p;
        adj_prot[posp] = d;
    }
    if (e < N_NODES) {
        int deg = (e < NUM_DRUGS) ? (drug_ptr[e + 1] - drug_ptr[e])
                                  : (prot_ptr[e + 1] - prot_ptr[e]);
        dinv[e] = rsqrtf((float)(deg + 1));
    }
}

// perm (rows grouped by cell line) via block-level two-phase allocation
__global__ void fill_perm(const int* __restrict__ ecl, int* curcl,
                          const int* __restrict__ cloff, int* __restrict__ perm) {
    __shared__ int lh[N_CL];
    __shared__ int gbase[N_CL];
    int t = threadIdx.x;
    int r = blockIdx.x * 256 + t;
    if (t < N_CL) lh[t] = 0;
    __syncthreads();
    int c = ecl[r];
    int lrank = atomicAdd(&lh[c], 1);
    __syncthreads();
    if (t < N_CL) gbase[t] = (lh[t] > 0) ? atomicAdd(&curcl[t * STRD], lh[t]) : 0;
    __syncthreads();
    perm[cloff[c] + gbase[c] + lrank] = r;
}

// ---------------------------------------------------------------------------
// fp32 -> (hi,lo) bf16 split, elementwise (coalesced)
__global__ void split_mat(const float* __restrict__ A, unsigned short* __restrict__ hi,
                          unsigned short* __restrict__ lo, int total) {
    int i = blockIdx.x * blockDim.x + threadIdx.x;
    if (i >= total) return;
    unsigned short h, l;
    split2(A[i], h, l);
    hi[i] = h; lo[i] = l;
}

// LDS-tiled transpose+split: W [m][K][N] fp32 -> [m][N][K] split bf16, coalesced
__global__ __launch_bounds__(256) void transpose_split64(const float* __restrict__ W,
                                                         unsigned short* __restrict__ hi,
                                                         unsigned short* __restrict__ lo,
                                                         int K, int N) {
    __shared__ float ld[64 * 65];
    int m = blockIdx.z;
    int k0 = blockIdx.x * 64, n0 = blockIdx.y * 64;
    const float* Wm = W + (size_t)m * K * N;
    int tx = threadIdx.x & 63, ty = threadIdx.x >> 6;
#pragma unroll
    for (int rr = 0; rr < 16; rr++) {
        int kl = rr * 4 + ty;
        ld[tx * 65 + kl] = Wm[(size_t)(k0 + kl) * N + n0 + tx];
    }
    __syncthreads();
    size_t obase = (size_t)m * N * K;
#pragma unroll
    for (int rr = 0; rr < 16; rr++) {
        int nl = rr * 4 + ty;
        float v = ld[nl * 65 + tx];
        unsigned short h, l;
        split2(v, h, l);
        size_t o = obase + (size_t)(n0 + nl) * K + k0 + tx;
        hi[o] = h;
        lo[o] = l;
    }
}

// ---------------------------------------------------------------------------
// split-bf16 MFMA GEMM: C[M,N] = A[M,K] @ B[K,N], B passed as B^T ([N][K]).
__global__ __launch_bounds__(256) void gemm_mfma(
        const unsigned short* __restrict__ Ahi, const unsigned short* __restrict__ Alo,
        const unsigned short* __restrict__ BThi, const unsigned short* __restrict__ BTlo,
        float* __restrict__ C, int M, int K, int N) {
    __shared__ unsigned short sAh[4096], sAl[4096], sBh[4096], sBl[4096];
    int t = threadIdx.x;
    int wv = t >> 6, lane = t & 63, quad = lane >> 4, l15 = lane & 15;
    int m0 = blockIdx.x * 128, n0 = blockIdx.y * 128;
    int m0w = (wv >> 1) * 64, n0w = (wv & 1) * 64;
    int srow = t >> 2;
    int skoff = (t & 3) * 8;
    floatx4 zero = {0.f, 0.f, 0.f, 0.f};
    floatx4 acc[4][4];
#pragma unroll
    for (int i = 0; i < 4; i++)
#pragma unroll
        for (int j = 0; j < 4; j++) acc[i][j] = zero;

    for (int kk = 0; kk < K; kk += 32) {
#pragma unroll
        for (int c = 0; c < 2; c++) {
            int arow = m0 + srow + c * 64; if (arow > M - 1) arow = M - 1;
            int brow = n0 + srow + c * 64; if (brow > N - 1) brow = N - 1;
            size_t aoff = (size_t)arow * K + kk + skoff;
            size_t boff = (size_t)brow * K + kk + skoff;
            int loff = (t + c * 256) * 8;
            gload16(Ahi + aoff, &sAh[loff]);
            gload16(Alo + aoff, &sAl[loff]);
            gload16(BThi + boff, &sBh[loff]);
            gload16(BTlo + boff, &sBl[loff]);
        }
        __syncthreads();
        short8 ah[4], al[4], bh[4], bl[4];
#pragma unroll
        for (int i = 0; i < 4; i++) {
            int r = (m0w + i * 16 + l15) * 32 + quad * 8;
            ah[i] = *(const short8*)&sAh[r];
            al[i] = *(const short8*)&sAl[r];
        }
#pragma unroll
        for (int j = 0; j < 4; j++) {
            int r = (n0w + j * 16 + l15) * 32 + quad * 8;
            bh[j] = *(const short8*)&sBh[r];
            bl[j] = *(const short8*)&sBl[r];
        }
#pragma unroll
        for (int i = 0; i < 4; i++)
#pragma unroll
            for (int j = 0; j < 4; j++) {
                acc[i][j] = __builtin_amdgcn_mfma_f32_16x16x32_bf16(ah[i], bh[j], acc[i][j], 0, 0, 0);
                acc[i][j] = __builtin_amdgcn_mfma_f32_16x16x32_bf16(ah[i], bl[j], acc[i][j], 0, 0, 0);
                acc[i][j] = __builtin_amdgcn_mfma_f32_16x16x32_bf16(al[i], bh[j], acc[i][j], 0, 0, 0);
            }
        __syncthreads();
    }
#pragma unroll
    for (int i = 0; i < 4; i++) {
        int gr = m0 + m0w + i * 16 + quad * 4;
#pragma unroll
        for (int r = 0; r < 4; r++) {
            if (gr + r < M) {
#pragma unroll
                for (int j = 0; j < 4; j++)
                    C[(size_t)(gr + r) * N + n0 + n0w + j * 16 + l15] = acc[i][j][r];
            }
        }
    }
}

// ---------------------------------------------------------------------------
// GCN aggregate (drug nodes use adj_drug, proteins adj_prot); optional bf16 split out
__global__ __launch_bounds__(256) void aggregate_k(const float* __restrict__ tmp,
                                                   const int* __restrict__ drug_ptr,
                                                   const int* __restrict__ adj_drug,
                                                   const int* __restrict__ prot_ptr,
                                                   const int* __restrict__ adj_prot,
                                                   const float* __restrict__ dinv,
                                                   const float* __restrict__ bias,
                                                   float* __restrict__ outf,
                                                   unsigned short* __restrict__ outhi,
                                                   unsigned short* __restrict__ outlo) {
    int wave = (blockIdx.x * blockDim.x + threadIdx.x) >> 6;
    int lane = threadIdx.x & 63;
    if (wave >= N_NODES) return;
    int i = wave;
    const int* adj;
    int s, e;
    if (i < NUM_DRUGS) { s = drug_ptr[i]; e = drug_ptr[i + 1]; adj = adj_drug; }
    else               { s = prot_ptr[i]; e = prot_ptr[i + 1]; adj = adj_prot; }
    float di = dinv[i];
    float4 self = ((const float4*)(tmp + (size_t)i * CDIM))[lane];
    float4 acc;
    acc.x = self.x * di; acc.y = self.y * di; acc.z = self.z * di; acc.w = self.w * di;
    for (int idx = s; idx < e; idx++) {
        int j = adj[idx];
        float dj = dinv[j];
        float4 v = ((const float4*)(tmp + (size_t)j * CDIM))[lane];
        acc.x = fmaf(v.x, dj, acc.x); acc.y = fmaf(v.y, dj, acc.y);
        acc.z = fmaf(v.z, dj, acc.z); acc.w = fmaf(v.w, dj, acc.w);
    }
    float4 bv = ((const float4*)bias)[lane];
    float4 r;
    r.x = fmaxf(fmaf(acc.x, di, bv.x), 0.f);
    r.y = fmaxf(fmaf(acc.y, di, bv.y), 0.f);
    r.z = fmaxf(fmaf(acc.z, di, bv.z), 0.f);
    r.w = fmaxf(fmaf(acc.w, di, bv.w), 0.f);
    if (outhi) {
        ushort4 h, l;
        split2(r.x, h.x, l.x); split2(r.y, h.y, l.y);
        split2(r.z, h.z, l.z); split2(r.w, h.w, l.w);
        *(ushort4*)&outhi[(size_t)i * CDIM + lane * 4] = h;
        *(ushort4*)&outlo[(size_t)i * CDIM + lane * 4] = l;
    } else {
        ((float4*)(outf + (size_t)i * CDIM))[lane] = r;
    }
}

// scatter-mean pool -> split-bf16 graph embeddings (reuses by-drug adjacency)
__global__ __launch_bounds__(256) void pool_drugs(const float* __restrict__ h2,
                                                  unsigned short* __restrict__ Ghi,
                                                  unsigned short* __restrict__ Glo,
                                                  const int* __restrict__ drug_ptr,
                                                  const int* __restrict__ adj_drug) {
    int wave = (blockIdx.x * blockDim.x + threadIdx.x) >> 6;
    int lane = threadIdx.x & 63;
    if (wave >= NUM_DRUGS) return;
    int d = wave;
    int s = drug_ptr[d], e = drug_ptr[d + 1];
    float4 acc = make_float4(0.f, 0.f, 0.f, 0.f);
    for (int idx = s; idx < e; idx++) {
        int p = adj_drug[idx];
        float4 v = ((const float4*)(h2 + (size_t)p * CDIM))[lane];
        acc.x += v.x; acc.y += v.y; acc.z += v.z; acc.w += v.w;
    }
    int cnt = e - s;
    float sc = 1.f / (float)(cnt > 1 ? cnt : 1);
    acc.x *= sc; acc.y *= sc; acc.z *= sc; acc.w *= sc;
    ushort4 h, l;
    split2(acc.x, h.x, l.x); split2(acc.y, h.y, l.y);
    split2(acc.z, h.z, l.z); split2(acc.w, h.w, l.w);
    *(ushort4*)&Ghi[(size_t)d * CDIM + lane * 4] = h;
    *(ushort4*)&Glo[(size_t)d * CDIM + lane * 4] = l;
}

__global__ void out_init(float* __restrict__ outp, const int* __restrict__ ecl,
                         const float* __restrict__ b2) {
    int i = blockIdx.x * blockDim.x + threadIdx.x;
    if (i < BATCH) outp[i] = b2[ecl[i]];
}

// ---------------------------------------------------------------------------
// grouped MoE MLP via split-bf16 MFMA; fused relu+b1 and [512,1] layer-2 epilogue
__global__ __launch_bounds__(256) void mlp_mfma(
        const unsigned short* __restrict__ Ghi, const unsigned short* __restrict__ Glo,
        const unsigned short* __restrict__ W1Thi, const unsigned short* __restrict__ W1Tlo,
        const float* __restrict__ b1, const float* __restrict__ W2,
        const int* __restrict__ ddb, const int* __restrict__ perm,
        const int* __restrict__ cloff, float* __restrict__ outp) {
    int e = blockIdx.z;
    int lo_ = cloff[e], hi_ = cloff[e + 1];
    int base = lo_ + blockIdx.y * 128;
    if (base >= hi_) return;
    __shared__ unsigned short sAh[4096], sAl[4096], sBh[4096], sBl[4096];
    __shared__ int rid[128], g0s[128], g1s[128];
    int t = threadIdx.x;
    if (t < 128) {
        int idx = base + t;
        if (idx < hi_) {
            int r = perm[idx];
            rid[t] = r;
            g0s[t] = ddb[r] * CDIM;
            g1s[t] = ddb[BATCH + r] * CDIM;
        } else {
            rid[t] = -1; g0s[t] = 0; g1s[t] = 0;
        }
    }
    __syncthreads();
    int wv = t >> 6, lane = t & 63, quad = lane >> 4, l15 = lane & 15;
    int n0 = blockIdx.x * 128;
    int m0w = (wv >> 1) * 64, n0w = (wv & 1) * 64;
    int srow = t >> 2;
    int skoff = (t & 3) * 8;
    const unsigned short* W1eh = W1Thi + (size_t)e * HID * HID;
    const unsigned short* W1el = W1Tlo + (size_t)e * HID * HID;
    floatx4 zero = {0.f, 0.f, 0.f, 0.f};
    floatx4 acc[4][4];
#pragma unroll
    for (int i = 0; i < 4; i++)
#pragma unroll
        for (int j = 0; j < 4; j++) acc[i][j] = zero;

    for (int kk = 0; kk < 2 * CDIM; kk += 32) {
        const int* gsel = (kk < CDIM) ? g0s : g1s;
        int kbase = kk & (CDIM - 1);
#pragma unroll
        for (int c = 0; c < 2; c++) {
            int arow = srow + c * 64;
            size_t aoff = (size_t)gsel[arow] + kbase + skoff;
            size_t boff = (size_t)(n0 + srow + c * 64) * HID + kk + skoff;
            int loff = (t + c * 256) * 8;
            gload16(Ghi + aoff, &sAh[loff]);
            gload16(Glo + aoff, &sAl[loff]);
            gload16(W1eh + boff, &sBh[loff]);
            gload16(W1el + boff, &sBl[loff]);
        }
        __syncthreads();
        short8 ah[4], al[4], bh[4], bl[4];
#pragma unroll
        for (int i = 0; i < 4; i++) {
            int r = (m0w + i * 16 + l15) * 32 + quad * 8;
            ah[i] = *(const short8*)&sAh[r];
            al[i] = *(const short8*)&sAl[r];
        }
#pragma unroll
        for (int j = 0; j < 4; j++) {
            int r = (n0w + j * 16 + l15) * 32 + quad * 8;
            bh[j] = *(const short8*)&sBh[r];
            bl[j] = *(const short8*)&sBl[r];
        }
#pragma unroll
        for (int i = 0; i < 4; i++)
#pragma unroll
            for (int j = 0; j < 4; j++) {
                acc[i][j] = __builtin_amdgcn_mfma_f32_16x16x32_bf16(ah[i], bh[j], acc[i][j], 0, 0, 0);
                acc[i][j] = __builtin_amdgcn_mfma_f32_16x16x32_bf16(ah[i], bl[j], acc[i][j], 0, 0, 0);
                acc[i][j] = __builtin_amdgcn_mfma_f32_16x16x32_bf16(al[i], bh[j], acc[i][j], 0, 0, 0);
            }
        __syncthreads();
    }
    const float* b1e = b1 + (size_t)e * HID;
    const float* W2e = W2 + (size_t)e * HID;
#pragma unroll
    for (int i = 0; i < 4; i++) {
#pragma unroll
        for (int r = 0; r < 4; r++) {
            float s = 0.f;
#pragma unroll
            for (int j = 0; j < 4; j++) {
                int col = n0 + n0w + j * 16 + l15;
                float h = fmaxf(acc[i][j][r] + b1e[col], 0.f);
                s = fmaf(h, W2e[col], s);
            }
            s += __shfl_xor(s, 1, 16);
            s += __shfl_xor(s, 2, 16);
            s += __shfl_xor(s, 4, 16);
            s += __shfl_xor(s, 8, 16);
            if (l15 == 0) {
                int rowl = m0w + i * 16 + quad * 4 + r;
                int rr = rid[rowl];
                if (rr >= 0) atomicAdd(&outp[rr], s);
            }
        }
    }
}

// ---------------------------------------------------------------------------
extern "C" void kernel_launch(void* const* d_in, const int* in_sizes, int n_in,
                              void* d_out, int out_size, void* d_ws, size_t ws_size,
                              hipStream_t stream) {
    const float* x   = (const float*)d_in[0];
    const int* ei    = (const int*)d_in[1];
    const int* ddb   = (const int*)d_in[2];
    const int* ecl   = (const int*)d_in[3];
    const float* Wg1 = (const float*)d_in[5];
    const float* bg1 = (const float*)d_in[6];
    const float* Wg2 = (const float*)d_in[7];
    const float* bg2 = (const float*)d_in[8];
    const float* W1  = (const float*)d_in[9];
    const float* b1  = (const float*)d_in[10];
    const float* W2  = (const float*)d_in[11];
    const float* b2  = (const float*)d_in[12];
    float* outp = (float*)d_out;

    char* p = (char*)d_ws;
    auto alloc = [&](size_t bytes) {
        char* r = p;
        p += (bytes + 255) & ~size_t(255);
        return (void*)r;
    };
    const size_t NC = (size_t)N_NODES * CDIM;
    float* tmp            = (float*)alloc(sizeof(float) * NC);
    unsigned short* h1hi  = (unsigned short*)alloc(2 * NC);
    unsigned short* h1lo  = (unsigned short*)alloc(2 * NC);
    char* xh2_blk         = (char*)alloc(4 * NC);                 // xhi+xlo, later h2
    unsigned short* xhi   = (unsigned short*)xh2_blk;
    unsigned short* xlo   = (unsigned short*)(xh2_blk + 2 * NC);
    float* h2             = (float*)xh2_blk;
    unsigned short* Ghi   = (unsigned short*)alloc(2 * NUM_DRUGS * CDIM);
    unsigned short* Glo   = (unsigned short*)alloc(2 * NUM_DRUGS * CDIM);
    unsigned short* wg1Th = (unsigned short*)alloc(2 * CDIM * CDIM);
    unsigned short* wg1Tl = (unsigned short*)alloc(2 * CDIM * CDIM);
    unsigned short* wg2Th = (unsigned short*)alloc(2 * CDIM * CDIM);
    unsigned short* wg2Tl = (unsigned short*)alloc(2 * CDIM * CDIM);
    unsigned short* W1Th  = (unsigned short*)alloc(2 * (size_t)N_CL * HID * HID);
    unsigned short* W1Tl  = (unsigned short*)alloc(2 * (size_t)N_CL * HID * HID);
    float* dinv    = (float*)alloc(sizeof(float) * N_NODES);
    int* cnt_d     = (int*)alloc(sizeof(int) * NUM_DRUGS * STRD);
    int* cur_d     = (int*)alloc(sizeof(int) * NUM_DRUGS * STRD);
    int* cnt_p     = (int*)alloc(sizeof(int) * N_NODES * STRP);
    int* cur_p     = (int*)alloc(sizeof(int) * N_NODES * STRP);
    int* drug_ptr  = (int*)alloc(sizeof(int) * (NUM_DRUGS + 1));
    int* prot_ptr  = (int*)alloc(sizeof(int) * (N_NODES + 1));
    int* adj_drug  = (int*)alloc(sizeof(int) * NUM_DPI);
    int* adj_prot  = (int*)alloc(sizeof(int) * NUM_DPI);
    int* clcnt     = (int*)alloc(sizeof(int) * N_CL * STRD);
    int* curcl     = (int*)alloc(sizeof(int) * N_CL * STRD);
    int* cloff     = (int*)alloc(sizeof(int) * (N_CL + 1));
    int* perm      = (int*)alloc(sizeof(int) * BATCH);

    // graph prep
    zero_counts<<<(N_NODES + 255) / 256, 256, 0, stream>>>(cnt_d, cur_d, cnt_p, cur_p,
                                                           clcnt, curcl);
    count_dpi<<<(NUM_DPI + 255) / 256, 256, 0, stream>>>(ei, cnt_d, cnt_p);
    count_cl<<<BATCH / 256, 256, 0, stream>>>(ecl, clcnt);
    scan3<<<3, 1024, 0, stream>>>(cnt_d, cnt_p, clcnt, drug_ptr, prot_ptr, cloff);
    fill_dpi<<<(NUM_DPI + 255) / 256, 256, 0, stream>>>(ei, drug_ptr, cur_d, adj_drug,
                                                        prot_ptr, cur_p, adj_prot, dinv);
    fill_perm<<<BATCH / 256, 256, 0, stream>>>(ecl, curcl, cloff, perm);
    // weight/activation splits (coalesced)
    split_mat<<<((int)NC + 255) / 256, 256, 0, stream>>>(x, xhi, xlo, (int)NC);
    transpose_split64<<<dim3(CDIM / 64, CDIM / 64, 1), 256, 0, stream>>>(
        Wg1, wg1Th, wg1Tl, CDIM, CDIM);
    transpose_split64<<<dim3(CDIM / 64, CDIM / 64, 1), 256, 0, stream>>>(
        Wg2, wg2Th, wg2Tl, CDIM, CDIM);
    transpose_split64<<<dim3(HID / 64, HID / 64, N_CL), 256, 0, stream>>>(
        W1, W1Th, W1Tl, HID, HID);
    // GCN layer 1
    gemm_mfma<<<dim3((N_NODES + 127) / 128, CDIM / 128), 256, 0, stream>>>(
        xhi, xlo, wg1Th, wg1Tl, tmp, N_NODES, CDIM, CDIM);
    aggregate_k<<<(N_NODES * 64 + 255) / 256, 256, 0, stream>>>(
        tmp, drug_ptr, adj_drug, prot_ptr, adj_prot, dinv, bg1, nullptr, h1hi, h1lo);
    // GCN layer 2
    gemm_mfma<<<dim3((N_NODES + 127) / 128, CDIM / 128), 256, 0, stream>>>(
        h1hi, h1lo, wg2Th, wg2Tl, tmp, N_NODES, CDIM, CDIM);
    aggregate_k<<<(N_NODES * 64 + 255) / 256, 256, 0, stream>>>(
        tmp, drug_ptr, adj_drug, prot_ptr, adj_prot, dinv, bg2, h2, nullptr, nullptr);
    // pool -> split graph embeddings
    pool_drugs<<<(NUM_DRUGS * 64 + 255) / 256, 256, 0, stream>>>(h2, Ghi, Glo,
                                                                 drug_ptr, adj_drug);
    // MoE MLP
    out_init<<<(BATCH + 255) / 256, 256, 0, stream>>>(outp, ecl, b2);
    mlp_mfma<<<dim3(HID / 128, 24, N_CL), 256, 0, stream>>>(
        Ghi, Glo, W1Th, W1Tl, b1, W2, ddb, perm, cloff, outp);
}

// Round 4
// 409.523 us; speedup vs baseline: 1.8002x; 1.2096x over previous
//
#include <hip/hip_runtime.h>
#include <hip/hip_bf16.h>

// Problem constants (fixed by reference)
#define N_NODES 20000
#define NUM_DRUGS 2048
#define NUM_DPI 200000
#define E2 400000          // 2*NUM_DPI directed edges
#define CDIM 256           // IN_C == EMB == 256
#define HID 512
#define N_CL 8
#define BATCH 16384

#define STRD 32            // drug/cl counter padding (ints) = 1 line per counter
#define STRP 16            // protein counter padding

typedef __attribute__((ext_vector_type(8))) short short8;   // 8 bf16 (MFMA A/B frag)
typedef __attribute__((ext_vector_type(4))) float floatx4;  // MFMA C/D frag

__device__ inline unsigned short f2bf(float f) {
    unsigned u = __float_as_uint(f);
    u += 0x7fff + ((u >> 16) & 1);   // RNE
    return (unsigned short)(u >> 16);
}
__device__ inline float bf2f(unsigned short h) {
    return __uint_as_float((unsigned)h << 16);
}
__device__ inline void split2(float v, unsigned short& h, unsigned short& l) {
    h = f2bf(v);
    l = f2bf(v - bf2f(h));
}
__device__ inline void gload16(const void* g, void* l) {
    __builtin_amdgcn_global_load_lds(
        (const __attribute__((address_space(1))) void*)g,
        (__attribute__((address_space(3))) void*)l, 16, 0, 0);
}
__device__ inline float4 f4fma(float4 v, float s, float4 a) {
    a.x = fmaf(v.x, s, a.x); a.y = fmaf(v.y, s, a.y);
    a.z = fmaf(v.z, s, a.z); a.w = fmaf(v.w, s, a.w);
    return a;
}

// ---------------------------------------------------------------------------
__global__ void zero_counts(int* cnt_d, int* cur_d, int* cnt_p, int* cur_p,
                            int* clcnt, int* curcl) {
    int i = blockIdx.x * blockDim.x + threadIdx.x;
    if (i < N_NODES) { cnt_p[i * STRP] = 0; cur_p[i * STRP] = 0; }
    if (i < NUM_DRUGS) { cnt_d[i * STRD] = 0; cur_d[i * STRD] = 0; }
    if (i < N_CL) { clcnt[i * STRD] = 0; curcl[i * STRD] = 0; }
}

// count DPI pairs into padded per-drug / per-protein histograms
__global__ void count_dpi(const int* __restrict__ ei, int* cnt_d, int* cnt_p) {
    int e = blockIdx.x * blockDim.x + threadIdx.x;
    if (e >= NUM_DPI) return;
    atomicAdd(&cnt_d[ei[e] * STRD], 1);          // drug id of pair e
    atomicAdd(&cnt_p[ei[E2 + e] * STRP], 1);     // protein id of pair e
}

// cell-line histogram via block-local LDS bins (16K atomics -> 512)
__global__ void count_cl(const int* __restrict__ ecl, int* clcnt) {
    __shared__ int lh[N_CL];
    int t = threadIdx.x;
    int r = blockIdx.x * 256 + t;
    if (t < N_CL) lh[t] = 0;
    __syncthreads();
    atomicAdd(&lh[ecl[r]], 1);
    __syncthreads();
    if (t < N_CL && lh[t] > 0) atomicAdd(&clcnt[t * STRD], lh[t]);
}

// generic strided single-block exclusive scan
__device__ void scan_dev(const int* counts, int stride, int* ptr, int n) {
    __shared__ int sums[1024];
    int t = threadIdx.x;
    int per = (n + 1023) / 1024;
    int start = t * per;
    int end = start + per; if (end > n) end = n;
    int s = 0;
    for (int i = start; i < end; i++) s += counts[i * stride];
    sums[t] = s;
    __syncthreads();
    for (int off = 1; off < 1024; off <<= 1) {
        int v = (t >= off) ? sums[t - off] : 0;
        __syncthreads();
        sums[t] += v;
        __syncthreads();
    }
    int base = (t == 0) ? 0 : sums[t - 1];
    for (int i = start; i < end; i++) {
        ptr[i] = base;
        base += counts[i * stride];
    }
    if (t == 1023) ptr[n] = sums[1023];
}

__global__ void scan3(const int* cnt_d, const int* cnt_p, const int* clcnt,
                      int* drug_ptr, int* prot_ptr, int* cloff) {
    if (blockIdx.x == 0) scan_dev(cnt_d, STRD, drug_ptr, NUM_DRUGS);
    else if (blockIdx.x == 1) scan_dev(cnt_p, STRP, prot_ptr, N_NODES);
    else scan_dev(clcnt, STRD, cloff, N_CL);
}

// fill both adjacency lists from DPI pairs; padded counters kill line ping-pong
__global__ void fill_dpi(const int* __restrict__ ei,
                         const int* __restrict__ drug_ptr, int* cur_d, int* adj_drug,
                         const int* __restrict__ prot_ptr, int* cur_p, int* adj_prot,
                         float* __restrict__ dinv) {
    int e = blockIdx.x * blockDim.x + threadIdx.x;
    if (e < NUM_DPI) {
        int d = ei[e];
        int p = ei[E2 + e];
        int posd = drug_ptr[d] + atomicAdd(&cur_d[d * STRD], 1);
        int posp = prot_ptr[p] + atomicAdd(&cur_p[p * STRP], 1);
        adj_drug[posd] = p;
        adj_prot[posp] = d;
    }
    if (e < N_NODES) {
        int deg = (e < NUM_DRUGS) ? (drug_ptr[e + 1] - drug_ptr[e])
                                  : (prot_ptr[e + 1] - prot_ptr[e]);
        dinv[e] = rsqrtf((float)(deg + 1));
    }
}

// perm (rows grouped by cell line) via block-level two-phase allocation
__global__ void fill_perm(const int* __restrict__ ecl, int* curcl,
                          const int* __restrict__ cloff, int* __restrict__ perm) {
    __shared__ int lh[N_CL];
    __shared__ int gbase[N_CL];
    int t = threadIdx.x;
    int r = blockIdx.x * 256 + t;
    if (t < N_CL) lh[t] = 0;
    __syncthreads();
    int c = ecl[r];
    int lrank = atomicAdd(&lh[c], 1);
    __syncthreads();
    if (t < N_CL) gbase[t] = (lh[t] > 0) ? atomicAdd(&curcl[t * STRD], lh[t]) : 0;
    __syncthreads();
    perm[cloff[c] + gbase[c] + lrank] = r;
}

// ---------------------------------------------------------------------------
// fp32 -> (hi,lo) bf16 split, elementwise (coalesced)
__global__ void split_mat(const float* __restrict__ A, unsigned short* __restrict__ hi,
                          unsigned short* __restrict__ lo, int total) {
    int i = blockIdx.x * blockDim.x + threadIdx.x;
    if (i >= total) return;
    unsigned short h, l;
    split2(A[i], h, l);
    hi[i] = h; lo[i] = l;
}

// LDS-tiled transpose+split: W [m][K][N] fp32 -> [m][N][K] split bf16, coalesced
__global__ __launch_bounds__(256) void transpose_split64(const float* __restrict__ W,
                                                         unsigned short* __restrict__ hi,
                                                         unsigned short* __restrict__ lo,
                                                         int K, int N) {
    __shared__ float ld[64 * 65];
    int m = blockIdx.z;
    int k0 = blockIdx.x * 64, n0 = blockIdx.y * 64;
    const float* Wm = W + (size_t)m * K * N;
    int tx = threadIdx.x & 63, ty = threadIdx.x >> 6;
#pragma unroll
    for (int rr = 0; rr < 16; rr++) {
        int kl = rr * 4 + ty;
        ld[tx * 65 + kl] = Wm[(size_t)(k0 + kl) * N + n0 + tx];
    }
    __syncthreads();
    size_t obase = (size_t)m * N * K;
#pragma unroll
    for (int rr = 0; rr < 16; rr++) {
        int nl = rr * 4 + ty;
        float v = ld[nl * 65 + tx];
        unsigned short h, l;
        split2(v, h, l);
        size_t o = obase + (size_t)(n0 + nl) * K + k0 + tx;
        hi[o] = h;
        lo[o] = l;
    }
}

// ---------------------------------------------------------------------------
// split-bf16 MFMA GEMM: C[M,N] = A[M,K] @ B[K,N], B passed as B^T ([N][K]).
__global__ __launch_bounds__(256) void gemm_mfma(
        const unsigned short* __restrict__ Ahi, const unsigned short* __restrict__ Alo,
        const unsigned short* __restrict__ BThi, const unsigned short* __restrict__ BTlo,
        float* __restrict__ C, int M, int K, int N) {
    __shared__ unsigned short sAh[4096], sAl[4096], sBh[4096], sBl[4096];
    int t = threadIdx.x;
    int wv = t >> 6, lane = t & 63, quad = lane >> 4, l15 = lane & 15;
    int m0 = blockIdx.x * 128, n0 = blockIdx.y * 128;
    int m0w = (wv >> 1) * 64, n0w = (wv & 1) * 64;
    int srow = t >> 2;
    int skoff = (t & 3) * 8;
    floatx4 zero = {0.f, 0.f, 0.f, 0.f};
    floatx4 acc[4][4];
#pragma unroll
    for (int i = 0; i < 4; i++)
#pragma unroll
        for (int j = 0; j < 4; j++) acc[i][j] = zero;

    for (int kk = 0; kk < K; kk += 32) {
#pragma unroll
        for (int c = 0; c < 2; c++) {
            int arow = m0 + srow + c * 64; if (arow > M - 1) arow = M - 1;
            int brow = n0 + srow + c * 64; if (brow > N - 1) brow = N - 1;
            size_t aoff = (size_t)arow * K + kk + skoff;
            size_t boff = (size_t)brow * K + kk + skoff;
            int loff = (t + c * 256) * 8;
            gload16(Ahi + aoff, &sAh[loff]);
            gload16(Alo + aoff, &sAl[loff]);
            gload16(BThi + boff, &sBh[loff]);
            gload16(BTlo + boff, &sBl[loff]);
        }
        __syncthreads();
        short8 ah[4], al[4], bh[4], bl[4];
#pragma unroll
        for (int i = 0; i < 4; i++) {
            int r = (m0w + i * 16 + l15) * 32 + quad * 8;
            ah[i] = *(const short8*)&sAh[r];
            al[i] = *(const short8*)&sAl[r];
        }
#pragma unroll
        for (int j = 0; j < 4; j++) {
            int r = (n0w + j * 16 + l15) * 32 + quad * 8;
            bh[j] = *(const short8*)&sBh[r];
            bl[j] = *(const short8*)&sBl[r];
        }
#pragma unroll
        for (int i = 0; i < 4; i++)
#pragma unroll
            for (int j = 0; j < 4; j++) {
                acc[i][j] = __builtin_amdgcn_mfma_f32_16x16x32_bf16(ah[i], bh[j], acc[i][j], 0, 0, 0);
                acc[i][j] = __builtin_amdgcn_mfma_f32_16x16x32_bf16(ah[i], bl[j], acc[i][j], 0, 0, 0);
                acc[i][j] = __builtin_amdgcn_mfma_f32_16x16x32_bf16(al[i], bh[j], acc[i][j], 0, 0, 0);
            }
        __syncthreads();
    }
#pragma unroll
    for (int i = 0; i < 4; i++) {
        int gr = m0 + m0w + i * 16 + quad * 4;
#pragma unroll
        for (int r = 0; r < 4; r++) {
            if (gr + r < M) {
#pragma unroll
                for (int j = 0; j < 4; j++)
                    C[(size_t)(gr + r) * N + n0 + n0w + j * 16 + l15] = acc[i][j][r];
            }
        }
    }
}

// ---------------------------------------------------------------------------
// GCN aggregate; 4-way unrolled neighbor loop for memory-level parallelism
__global__ __launch_bounds__(256) void aggregate_k(const float* __restrict__ tmp,
                                                   const int* __restrict__ drug_ptr,
                                                   const int* __restrict__ adj_drug,
                                                   const int* __restrict__ prot_ptr,
                                                   const int* __restrict__ adj_prot,
                                                   const float* __restrict__ dinv,
                                                   const float* __restrict__ bias,
                                                   float* __restrict__ outf,
                                                   unsigned short* __restrict__ outhi,
                                                   unsigned short* __restrict__ outlo) {
    int wave = (blockIdx.x * blockDim.x + threadIdx.x) >> 6;
    int lane = threadIdx.x & 63;
    if (wave >= N_NODES) return;
    int i = wave;
    const int* adj;
    int s, e;
    if (i < NUM_DRUGS) { s = drug_ptr[i]; e = drug_ptr[i + 1]; adj = adj_drug; }
    else               { s = prot_ptr[i]; e = prot_ptr[i + 1]; adj = adj_prot; }
    float di = dinv[i];
    float4 a0 = make_float4(0.f, 0.f, 0.f, 0.f);
    float4 a1 = a0, a2 = a0, a3 = a0;
    int idx = s;
    for (; idx + 4 <= e; idx += 4) {
        int j0 = adj[idx + 0], j1 = adj[idx + 1], j2 = adj[idx + 2], j3 = adj[idx + 3];
        float d0 = dinv[j0], d1 = dinv[j1], d2 = dinv[j2], d3 = dinv[j3];
        float4 v0 = ((const float4*)(tmp + (size_t)j0 * CDIM))[lane];
        float4 v1 = ((const float4*)(tmp + (size_t)j1 * CDIM))[lane];
        float4 v2 = ((const float4*)(tmp + (size_t)j2 * CDIM))[lane];
        float4 v3 = ((const float4*)(tmp + (size_t)j3 * CDIM))[lane];
        a0 = f4fma(v0, d0, a0);
        a1 = f4fma(v1, d1, a1);
        a2 = f4fma(v2, d2, a2);
        a3 = f4fma(v3, d3, a3);
    }
    for (; idx < e; idx++) {
        int j = adj[idx];
        float dj = dinv[j];
        float4 v = ((const float4*)(tmp + (size_t)j * CDIM))[lane];
        a0 = f4fma(v, dj, a0);
    }
    float4 self = ((const float4*)(tmp + (size_t)i * CDIM))[lane];
    float4 acc;
    acc.x = (a0.x + a1.x) + (a2.x + a3.x) + self.x * di;
    acc.y = (a0.y + a1.y) + (a2.y + a3.y) + self.y * di;
    acc.z = (a0.z + a1.z) + (a2.z + a3.z) + self.z * di;
    acc.w = (a0.w + a1.w) + (a2.w + a3.w) + self.w * di;
    float4 bv = ((const float4*)bias)[lane];
    float4 r;
    r.x = fmaxf(fmaf(acc.x, di, bv.x), 0.f);
    r.y = fmaxf(fmaf(acc.y, di, bv.y), 0.f);
    r.z = fmaxf(fmaf(acc.z, di, bv.z), 0.f);
    r.w = fmaxf(fmaf(acc.w, di, bv.w), 0.f);
    if (outhi) {
        ushort4 h, l;
        split2(r.x, h.x, l.x); split2(r.y, h.y, l.y);
        split2(r.z, h.z, l.z); split2(r.w, h.w, l.w);
        *(ushort4*)&outhi[(size_t)i * CDIM + lane * 4] = h;
        *(ushort4*)&outlo[(size_t)i * CDIM + lane * 4] = l;
    } else {
        ((float4*)(outf + (size_t)i * CDIM))[lane] = r;
    }
}

// scatter-mean pool -> split-bf16 graph embeddings; 4-way unrolled
__global__ __launch_bounds__(256) void pool_drugs(const float* __restrict__ h2,
                                                  unsigned short* __restrict__ Ghi,
                                                  unsigned short* __restrict__ Glo,
                                                  const int* __restrict__ drug_ptr,
                                                  const int* __restrict__ adj_drug) {
    int wave = (blockIdx.x * blockDim.x + threadIdx.x) >> 6;
    int lane = threadIdx.x & 63;
    if (wave >= NUM_DRUGS) return;
    int d = wave;
    int s = drug_ptr[d], e = drug_ptr[d + 1];
    float4 a0 = make_float4(0.f, 0.f, 0.f, 0.f);
    float4 a1 = a0, a2 = a0, a3 = a0;
    int idx = s;
    for (; idx + 4 <= e; idx += 4) {
        int j0 = adj_drug[idx + 0], j1 = adj_drug[idx + 1];
        int j2 = adj_drug[idx + 2], j3 = adj_drug[idx + 3];
        float4 v0 = ((const float4*)(h2 + (size_t)j0 * CDIM))[lane];
        float4 v1 = ((const float4*)(h2 + (size_t)j1 * CDIM))[lane];
        float4 v2 = ((const float4*)(h2 + (size_t)j2 * CDIM))[lane];
        float4 v3 = ((const float4*)(h2 + (size_t)j3 * CDIM))[lane];
        a0.x += v0.x; a0.y += v0.y; a0.z += v0.z; a0.w += v0.w;
        a1.x += v1.x; a1.y += v1.y; a1.z += v1.z; a1.w += v1.w;
        a2.x += v2.x; a2.y += v2.y; a2.z += v2.z; a2.w += v2.w;
        a3.x += v3.x; a3.y += v3.y; a3.z += v3.z; a3.w += v3.w;
    }
    for (; idx < e; idx++) {
        int j = adj_drug[idx];
        float4 v = ((const float4*)(h2 + (size_t)j * CDIM))[lane];
        a0.x += v.x; a0.y += v.y; a0.z += v.z; a0.w += v.w;
    }
    float4 acc;
    acc.x = (a0.x + a1.x) + (a2.x + a3.x);
    acc.y = (a0.y + a1.y) + (a2.y + a3.y);
    acc.z = (a0.z + a1.z) + (a2.z + a3.z);
    acc.w = (a0.w + a1.w) + (a2.w + a3.w);
    int cnt = e - s;
    float sc = 1.f / (float)(cnt > 1 ? cnt : 1);
    acc.x *= sc; acc.y *= sc; acc.z *= sc; acc.w *= sc;
    ushort4 h, l;
    split2(acc.x, h.x, l.x); split2(acc.y, h.y, l.y);
    split2(acc.z, h.z, l.z); split2(acc.w, h.w, l.w);
    *(ushort4*)&Ghi[(size_t)d * CDIM + lane * 4] = h;
    *(ushort4*)&Glo[(size_t)d * CDIM + lane * 4] = l;
}

__global__ void out_init(float* __restrict__ outp, const int* __restrict__ ecl,
                         const float* __restrict__ b2) {
    int i = blockIdx.x * blockDim.x + threadIdx.x;
    if (i < BATCH) outp[i] = b2[ecl[i]];
}

// ---------------------------------------------------------------------------
// grouped MoE MLP via split-bf16 MFMA; fused relu+b1 and [512,1] layer-2 epilogue
__global__ __launch_bounds__(256) void mlp_mfma(
        const unsigned short* __restrict__ Ghi, const unsigned short* __restrict__ Glo,
        const unsigned short* __restrict__ W1Thi, const unsigned short* __restrict__ W1Tlo,
        const float* __restrict__ b1, const float* __restrict__ W2,
        const int* __restrict__ ddb, const int* __restrict__ perm,
        const int* __restrict__ cloff, float* __restrict__ outp) {
    int e = blockIdx.z;
    int lo_ = cloff[e], hi_ = cloff[e + 1];
    int base = lo_ + blockIdx.y * 128;
    if (base >= hi_) return;
    __shared__ unsigned short sAh[4096], sAl[4096], sBh[4096], sBl[4096];
    __shared__ int rid[128], g0s[128], g1s[128];
    int t = threadIdx.x;
    if (t < 128) {
        int idx = base + t;
        if (idx < hi_) {
            int r = perm[idx];
            rid[t] = r;
            g0s[t] = ddb[r] * CDIM;
            g1s[t] = ddb[BATCH + r] * CDIM;
        } else {
            rid[t] = -1; g0s[t] = 0; g1s[t] = 0;
        }
    }
    __syncthreads();
    int wv = t >> 6, lane = t & 63, quad = lane >> 4, l15 = lane & 15;
    int n0 = blockIdx.x * 128;
    int m0w = (wv >> 1) * 64, n0w = (wv & 1) * 64;
    int srow = t >> 2;
    int skoff = (t & 3) * 8;
    const unsigned short* W1eh = W1Thi + (size_t)e * HID * HID;
    const unsigned short* W1el = W1Tlo + (size_t)e * HID * HID;
    floatx4 zero = {0.f, 0.f, 0.f, 0.f};
    floatx4 acc[4][4];
#pragma unroll
    for (int i = 0; i < 4; i++)
#pragma unroll
        for (int j = 0; j < 4; j++) acc[i][j] = zero;

    for (int kk = 0; kk < 2 * CDIM; kk += 32) {
        const int* gsel = (kk < CDIM) ? g0s : g1s;
        int kbase = kk & (CDIM - 1);
#pragma unroll
        for (int c = 0; c < 2; c++) {
            int arow = srow + c * 64;
            size_t aoff = (size_t)gsel[arow] + kbase + skoff;
            size_t boff = (size_t)(n0 + srow + c * 64) * HID + kk + skoff;
            int loff = (t + c * 256) * 8;
            gload16(Ghi + aoff, &sAh[loff]);
            gload16(Glo + aoff, &sAl[loff]);
            gload16(W1eh + boff, &sBh[loff]);
            gload16(W1el + boff, &sBl[loff]);
        }
        __syncthreads();
        short8 ah[4], al[4], bh[4], bl[4];
#pragma unroll
        for (int i = 0; i < 4; i++) {
            int r = (m0w + i * 16 + l15) * 32 + quad * 8;
            ah[i] = *(const short8*)&sAh[r];
            al[i] = *(const short8*)&sAl[r];
        }
#pragma unroll
        for (int j = 0; j < 4; j++) {
            int r = (n0w + j * 16 + l15) * 32 + quad * 8;
            bh[j] = *(const short8*)&sBh[r];
            bl[j] = *(const short8*)&sBl[r];
        }
#pragma unroll
        for (int i = 0; i < 4; i++)
#pragma unroll
            for (int j = 0; j < 4; j++) {
                acc[i][j] = __builtin_amdgcn_mfma_f32_16x16x32_bf16(ah[i], bh[j], acc[i][j], 0, 0, 0);
                acc[i][j] = __builtin_amdgcn_mfma_f32_16x16x32_bf16(ah[i], bl[j], acc[i][j], 0, 0, 0);
                acc[i][j] = __builtin_amdgcn_mfma_f32_16x16x32_bf16(al[i], bh[j], acc[i][j], 0, 0, 0);
            }
        __syncthreads();
    }
    const float* b1e = b1 + (size_t)e * HID;
    const float* W2e = W2 + (size_t)e * HID;
#pragma unroll
    for (int i = 0; i < 4; i++) {
#pragma unroll
        for (int r = 0; r < 4; r++) {
            float s = 0.f;
#pragma unroll
            for (int j = 0; j < 4; j++) {
                int col = n0 + n0w + j * 16 + l15;
                float h = fmaxf(acc[i][j][r] + b1e[col], 0.f);
                s = fmaf(h, W2e[col], s);
            }
            s += __shfl_xor(s, 1, 16);
            s += __shfl_xor(s, 2, 16);
            s += __shfl_xor(s, 4, 16);
            s += __shfl_xor(s, 8, 16);
            if (l15 == 0) {
                int rowl = m0w + i * 16 + quad * 4 + r;
                int rr = rid[rowl];
                if (rr >= 0) atomicAdd(&outp[rr], s);
            }
        }
    }
}

// ---------------------------------------------------------------------------
extern "C" void kernel_launch(void* const* d_in, const int* in_sizes, int n_in,
                              void* d_out, int out_size, void* d_ws, size_t ws_size,
                              hipStream_t stream) {
    const float* x   = (const float*)d_in[0];
    const int* ei    = (const int*)d_in[1];
    const int* ddb   = (const int*)d_in[2];
    const int* ecl   = (const int*)d_in[3];
    const float* Wg1 = (const float*)d_in[5];
    const float* bg1 = (const float*)d_in[6];
    const float* Wg2 = (const float*)d_in[7];
    const float* bg2 = (const float*)d_in[8];
    const float* W1  = (const float*)d_in[9];
    const float* b1  = (const float*)d_in[10];
    const float* W2  = (const float*)d_in[11];
    const float* b2  = (const float*)d_in[12];
    float* outp = (float*)d_out;

    char* p = (char*)d_ws;
    auto alloc = [&](size_t bytes) {
        char* r = p;
        p += (bytes + 255) & ~size_t(255);
        return (void*)r;
    };
    const size_t NC = (size_t)N_NODES * CDIM;
    float* tmp            = (float*)alloc(sizeof(float) * NC);
    unsigned short* h1hi  = (unsigned short*)alloc(2 * NC);
    unsigned short* h1lo  = (unsigned short*)alloc(2 * NC);
    char* xh2_blk         = (char*)alloc(4 * NC);                 // xhi+xlo, later h2
    unsigned short* xhi   = (unsigned short*)xh2_blk;
    unsigned short* xlo   = (unsigned short*)(xh2_blk + 2 * NC);
    float* h2             = (float*)xh2_blk;
    unsigned short* Ghi   = (unsigned short*)alloc(2 * NUM_DRUGS * CDIM);
    unsigned short* Glo   = (unsigned short*)alloc(2 * NUM_DRUGS * CDIM);
    unsigned short* wg1Th = (unsigned short*)alloc(2 * CDIM * CDIM);
    unsigned short* wg1Tl = (unsigned short*)alloc(2 * CDIM * CDIM);
    unsigned short* wg2Th = (unsigned short*)alloc(2 * CDIM * CDIM);
    unsigned short* wg2Tl = (unsigned short*)alloc(2 * CDIM * CDIM);
    unsigned short* W1Th  = (unsigned short*)alloc(2 * (size_t)N_CL * HID * HID);
    unsigned short* W1Tl  = (unsigned short*)alloc(2 * (size_t)N_CL * HID * HID);
    float* dinv    = (float*)alloc(sizeof(float) * N_NODES);
    int* cnt_d     = (int*)alloc(sizeof(int) * NUM_DRUGS * STRD);
    int* cur_d     = (int*)alloc(sizeof(int) * NUM_DRUGS * STRD);
    int* cnt_p     = (int*)alloc(sizeof(int) * N_NODES * STRP);
    int* cur_p     = (int*)alloc(sizeof(int) * N_NODES * STRP);
    int* drug_ptr  = (int*)alloc(sizeof(int) * (NUM_DRUGS + 1));
    int* prot_ptr  = (int*)alloc(sizeof(int) * (N_NODES + 1));
    int* adj_drug  = (int*)alloc(sizeof(int) * NUM_DPI);
    int* adj_prot  = (int*)alloc(sizeof(int) * NUM_DPI);
    int* clcnt     = (int*)alloc(sizeof(int) * N_CL * STRD);
    int* curcl     = (int*)alloc(sizeof(int) * N_CL * STRD);
    int* cloff     = (int*)alloc(sizeof(int) * (N_CL + 1));
    int* perm      = (int*)alloc(sizeof(int) * BATCH);

    // graph prep
    zero_counts<<<(N_NODES + 255) / 256, 256, 0, stream>>>(cnt_d, cur_d, cnt_p, cur_p,
                                                           clcnt, curcl);
    count_dpi<<<(NUM_DPI + 255) / 256, 256, 0, stream>>>(ei, cnt_d, cnt_p);
    count_cl<<<BATCH / 256, 256, 0, stream>>>(ecl, clcnt);
    scan3<<<3, 1024, 0, stream>>>(cnt_d, cnt_p, clcnt, drug_ptr, prot_ptr, cloff);
    fill_dpi<<<(NUM_DPI + 255) / 256, 256, 0, stream>>>(ei, drug_ptr, cur_d, adj_drug,
                                                        prot_ptr, cur_p, adj_prot, dinv);
    fill_perm<<<BATCH / 256, 256, 0, stream>>>(ecl, curcl, cloff, perm);
    // weight/activation splits (coalesced)
    split_mat<<<((int)NC + 255) / 256, 256, 0, stream>>>(x, xhi, xlo, (int)NC);
    transpose_split64<<<dim3(CDIM / 64, CDIM / 64, 1), 256, 0, stream>>>(
        Wg1, wg1Th, wg1Tl, CDIM, CDIM);
    transpose_split64<<<dim3(CDIM / 64, CDIM / 64, 1), 256, 0, stream>>>(
        Wg2, wg2Th, wg2Tl, CDIM, CDIM);
    transpose_split64<<<dim3(HID / 64, HID / 64, N_CL), 256, 0, stream>>>(
        W1, W1Th, W1Tl, HID, HID);
    // GCN layer 1
    gemm_mfma<<<dim3((N_NODES + 127) / 128, CDIM / 128), 256, 0, stream>>>(
        xhi, xlo, wg1Th, wg1Tl, tmp, N_NODES, CDIM, CDIM);
    aggregate_k<<<(N_NODES * 64 + 255) / 256, 256, 0, stream>>>(
        tmp, drug_ptr, adj_drug, prot_ptr, adj_prot, dinv, bg1, nullptr, h1hi, h1lo);
    // GCN layer 2
    gemm_mfma<<<dim3((N_NODES + 127) / 128, CDIM / 128), 256, 0, stream>>>(
        h1hi, h1lo, wg2Th, wg2Tl, tmp, N_NODES, CDIM, CDIM);
    aggregate_k<<<(N_NODES * 64 + 255) / 256, 256, 0, stream>>>(
        tmp, drug_ptr, adj_drug, prot_ptr, adj_prot, dinv, bg2, h2, nullptr, nullptr);
    // pool -> split graph embeddings
    pool_drugs<<<(NUM_DRUGS * 64 + 255) / 256, 256, 0, stream>>>(h2, Ghi, Glo,
                                                                 drug_ptr, adj_drug);
    // MoE MLP
    out_init<<<(BATCH + 255) / 256, 256, 0, stream>>>(outp, ecl, b2);
    mlp_mfma<<<dim3(HID / 128, 24, N_CL), 256, 0, stream>>>(
        Ghi, Glo, W1Th, W1Tl, b1, W2, ddb, perm, cloff, outp);
}